// Round 10
// baseline (704.370 us; speedup 1.0000x reference)
//
#include <hip/hip_runtime.h>
#include <cstddef>

#define DB 4
#define DL 1024
#define DD 1024
#define DH 16
#define DF 4096

typedef __attribute__((ext_vector_type(8))) short short8;
typedef __attribute__((ext_vector_type(4))) float float4v;

static __device__ __forceinline__ short f2bf(float f) {
    unsigned u = __float_as_uint(f);
    unsigned r = (u + 0x7FFFu + ((u >> 16) & 1u)) >> 16;   // RNE
    return (short)r;
}

#define GLOAD_LDS16(gp, lp)                                                          \
    __builtin_amdgcn_global_load_lds(                                                \
        (const __attribute__((address_space(1))) void*)(gp),                         \
        (__attribute__((address_space(3))) void*)(lp), 16, 0, 0)

// ---------------------------------------------------------------- mega-prep
__global__ __launch_bounds__(256) void prep_all_kernel(
    const float* __restrict__ Wdc, const float* __restrict__ Wdec,
    const float* __restrict__ Wq, const float* __restrict__ Wk,
    const float* __restrict__ Wv, const float* __restrict__ Wo,
    const float* __restrict__ W1, const float* __restrict__ W2,
    const float* __restrict__ x, const float* __restrict__ agg,
    short* __restrict__ wdc_bt, short* __restrict__ wdec_bt,
    short* __restrict__ wq4t, short* __restrict__ wkvt, short* __restrict__ wot,
    short* __restrict__ w1t, short* __restrict__ w2t, short* __restrict__ xpad,
    float* __restrict__ wagg, float* __restrict__ aux) {
    __shared__ float tile[32][33];
    const size_t M1 = 1024 * 1024;
    int blk = blockIdx.x, tid = threadIdx.x;
    if (blk < 12288) {
        int idx = blk * 256 + tid;
        int i = idx & 1023, o = (idx >> 10) & 1023, k = idx >> 20;
        wdc_bt[idx] = f2bf(Wdc[((size_t)o * 1024 + i) * 3 + k]);
        return;
    }
    if (blk < 36864) {
        int idx = (blk - 12288) * 256 + tid;
        int i = idx & 1023, k2 = (idx >> 10) & 1, n = (idx >> 11) & 1023, s = idx >> 21;
        wdec_bt[idx] = f2bf(Wdec[(((size_t)(s * 1024 + n)) * 1024 + i) * 2 + k2]);
        return;
    }
    if (blk < 58368) {
        const float* src; short* dst; int K, N, bx, by;
        if (blk < 50176) {
            int r = blk - 36864;
            int z = r >> 10, rem = r & 1023;
            bx = rem & 31; by = rem >> 5; K = 1024; N = 1024;
            if (z < 4)      { src = Wq + (size_t)z * M1;       dst = wq4t + (size_t)z * M1; }
            else if (z < 8) { src = Wk + (size_t)(z - 4) * M1; dst = wkvt + (size_t)(z - 4) * 2 * M1; }
            else if (z < 12){ src = Wv;                        dst = wkvt + (size_t)(z - 8) * 2 * M1 + M1; }
            else            { src = Wo;                        dst = wot; }
        } else if (blk < 54272) {
            int r = blk - 50176;
            bx = r & 127; by = r >> 7; K = 1024; N = 4096; src = W1; dst = w1t;
        } else {
            int r = blk - 54272;
            bx = r & 31; by = r >> 5; K = 4096; N = 1024; src = W2; dst = w2t;
        }
        int n0 = bx << 5, k0 = by << 5;
        int cc = tid & 31, rr = tid >> 5;
#pragma unroll
        for (int p = 0; p < 4; p++) {
            int kk = (p << 3) + rr;
            tile[kk][cc] = src[(size_t)(k0 + kk) * N + n0 + cc];
        }
        __syncthreads();
#pragma unroll
        for (int p = 0; p < 4; p++) {
            int nn = (p << 3) + rr;
            dst[(size_t)(n0 + nn) * K + k0 + cc] = f2bf(tile[cc][nn]);
        }
        return;
    }
    if (blk < 74816) {
        int idx = (blk - 58368) * 256 + tid;
        int d = idx & 1023;
        int row = (idx >> 10) % 1028;
        int b = (idx >> 10) / 1028;
        int l = row - 2;
        float v = (l >= 0 && l < DL) ? x[((size_t)(b * DL + l)) * DD + d] : 0.f;
        xpad[idx] = f2bf(v);
        return;
    }
    if (tid == 0) {
        float l0 = agg[0], l1 = agg[1], l2 = agg[2], l3 = agg[3];
        float m = fmaxf(fmaxf(l0, l1), fmaxf(l2, l3));
        float e0 = __expf(l0 - m), e1 = __expf(l1 - m);
        float e2 = __expf(l2 - m), e3 = __expf(l3 - m);
        float ssum = e0 + e1 + e2 + e3;
        float w0 = e0 / ssum, w1 = e1 / ssum, w2 = e2 / ssum, w3 = e3 / ssum;
        wagg[0] = w0; wagg[1] = w1; wagg[2] = w2; wagg[3] = w3;
        *aux = -(w0 * logf(w0 + 1e-9f) + w1 * logf(w1 + 1e-9f) +
                 w2 * logf(w2 + 1e-9f) + w3 * logf(w3 + 1e-9f));
    }
}

// ---------------------------------------------------------------- MFMA GEMM
// Measured-best schedule (round 7): double-buffered LDS, tile t+1's
// global_load_lds issued at step TOP, single __syncthreads() at step BOTTOM.
// (T2 read-swizzle and counted-vmcnt both refuted by A/B: conflicts counter
// is stage-write-dominated/saturated; swizzled sources broke coalescing.)
// Epilogue stores NONTEMPORAL: 2B-granular C writes were ~2x amplified
// (WRITE_SIZE 67MB vs 32MB data) via line allocation.
template <int ACT, int OBF>
__global__ __launch_bounds__(256) void mgemm_kernel(
    const short* __restrict__ A, const short* __restrict__ Bt,
    const float* __restrict__ bias, void* __restrict__ Cv,
    int M, int N, int K) {
    __shared__ short As[2][128 * 32];
    __shared__ short Bs[2][128 * 32];
    int tid = threadIdx.x;
    int wave = tid >> 6, lane = tid & 63;
    int lq = lane & 15, quad = lane >> 4;
    int m0 = blockIdx.y << 7, n0 = blockIdx.x << 7;
    int wm = (wave & 1) << 6, wn = (wave >> 1) << 6;
    int r0 = tid >> 2, r1 = (256 + tid) >> 2;
    int kc0 = (tid & 3) << 3;
    const short* Ag0 = A + (size_t)(m0 + r0) * K + kc0;
    const short* Ag1 = A + (size_t)(m0 + r1) * K + kc0;
    const short* Bg0 = Bt + (size_t)(n0 + r0) * K + kc0;
    const short* Bg1 = Bt + (size_t)(n0 + r1) * K + kc0;
    float4v acc[4][4];
#pragma unroll
    for (int mi = 0; mi < 4; mi++)
#pragma unroll
        for (int ni = 0; ni < 4; ni++) acc[mi][ni] = (float4v){0.f, 0.f, 0.f, 0.f};

#define MG_STAGE(BUF, KO)                                                \
    {                                                                    \
        GLOAD_LDS16(Ag0 + (KO), As[BUF] + tid * 8);                      \
        GLOAD_LDS16(Ag1 + (KO), As[BUF] + (256 + tid) * 8);              \
        GLOAD_LDS16(Bg0 + (KO), Bs[BUF] + tid * 8);                      \
        GLOAD_LDS16(Bg1 + (KO), Bs[BUF] + (256 + tid) * 8);              \
    }
    int nk = K >> 5;
    MG_STAGE(0, 0);
    __syncthreads();
    for (int t = 0; t < nk; t++) {
        int cur = t & 1;
        if (t + 1 < nk) MG_STAGE(cur ^ 1, (t + 1) << 5);
        short8 af[4], bfr[4];
#pragma unroll
        for (int mi = 0; mi < 4; mi++)
            af[mi] = *(const short8*)(As[cur] + ((wm + (mi << 4) + lq) << 5) + (quad << 3));
#pragma unroll
        for (int ni = 0; ni < 4; ni++)
            bfr[ni] = *(const short8*)(Bs[cur] + ((wn + (ni << 4) + lq) << 5) + (quad << 3));
#pragma unroll
        for (int mi = 0; mi < 4; mi++)
#pragma unroll
            for (int ni = 0; ni < 4; ni++)
                acc[mi][ni] = __builtin_amdgcn_mfma_f32_16x16x32_bf16(
                    af[mi], bfr[ni], acc[mi][ni], 0, 0, 0);
        __syncthreads();
    }
#undef MG_STAGE
#pragma unroll
    for (int ni = 0; ni < 4; ni++) {
        int col = n0 + wn + (ni << 4) + lq;
        float bv = bias ? bias[col] : 0.f;
#pragma unroll
        for (int mi = 0; mi < 4; mi++) {
#pragma unroll
            for (int r = 0; r < 4; r++) {
                int row = m0 + wm + (mi << 4) + (quad << 2) + r;
                float v = acc[mi][ni][r] + bv;
                if (ACT == 1) v = 0.5f * v * (1.0f + erff(v * 0.70710678118654752f));
                if (OBF)
                    __builtin_nontemporal_store(f2bf(v),
                        &((short*)Cv)[(size_t)row * N + col]);
                else
                    __builtin_nontemporal_store(v,
                        &((float*)Cv)[(size_t)row * N + col]);
            }
        }
    }
}

// ---------------------------------------------------------------- grouped KV GEMM
// K-half columns written directly in K-fragment layout; V-half row-major.
// Measured-best dbuf schedule; nt epilogue stores.
__global__ __launch_bounds__(256) void kvgemm_kernel(
    const short* __restrict__ acts, const short* __restrict__ wkvt,
    short* __restrict__ kvall, short* __restrict__ kfrall) {
    __shared__ short As[2][128 * 32];
    __shared__ short Bs[2][128 * 32];
    int my = blockIdx.y;                       // 0..59
    int s = my < 32 ? 0 : my < 48 ? 1 : my < 56 ? 2 : 3;
    int m0 = my << 7;
    int rb = s == 0 ? 0 : s == 1 ? 4096 : s == 2 ? 6144 : 7168;
    size_t doff = s == 0 ? 0 : s == 1 ? 4194304 : s == 2 ? 6291456 : 7340032;
    int Ls = DL >> s;
    const short* Bt = wkvt + (size_t)s * 2097152;
    const int K = 1024, N = 2048;
    int tid = threadIdx.x;
    int wave = tid >> 6, lane = tid & 63;
    int lq = lane & 15, quad = lane >> 4;
    int n0 = blockIdx.x << 7;
    int wm = (wave & 1) << 6, wn = (wave >> 1) << 6;
    int r0 = tid >> 2, r1 = (256 + tid) >> 2;
    int kc0 = (tid & 3) << 3;
    const short* Ag0 = acts + (size_t)(m0 + r0) * K + kc0;
    const short* Ag1 = acts + (size_t)(m0 + r1) * K + kc0;
    const short* Bg0 = Bt + (size_t)(n0 + r0) * K + kc0;
    const short* Bg1 = Bt + (size_t)(n0 + r1) * K + kc0;
    float4v acc[4][4];
#pragma unroll
    for (int mi = 0; mi < 4; mi++)
#pragma unroll
        for (int ni = 0; ni < 4; ni++) acc[mi][ni] = (float4v){0.f, 0.f, 0.f, 0.f};

#define KV_STAGE(BUF, KO)                                                \
    {                                                                    \
        GLOAD_LDS16(Ag0 + (KO), As[BUF] + tid * 8);                      \
        GLOAD_LDS16(Ag1 + (KO), As[BUF] + (256 + tid) * 8);              \
        GLOAD_LDS16(Bg0 + (KO), Bs[BUF] + tid * 8);                      \
        GLOAD_LDS16(Bg1 + (KO), Bs[BUF] + (256 + tid) * 8);              \
    }
    int nk = K >> 5;
    KV_STAGE(0, 0);
    __syncthreads();
    for (int t = 0; t < nk; t++) {
        int cur = t & 1;
        if (t + 1 < nk) KV_STAGE(cur ^ 1, (t + 1) << 5);
        short8 af[4], bfr[4];
#pragma unroll
        for (int mi = 0; mi < 4; mi++)
            af[mi] = *(const short8*)(As[cur] + ((wm + (mi << 4) + lq) << 5) + (quad << 3));
#pragma unroll
        for (int ni = 0; ni < 4; ni++)
            bfr[ni] = *(const short8*)(Bs[cur] + ((wn + (ni << 4) + lq) << 5) + (quad << 3));
#pragma unroll
        for (int mi = 0; mi < 4; mi++)
#pragma unroll
            for (int ni = 0; ni < 4; ni++)
                acc[mi][ni] = __builtin_amdgcn_mfma_f32_16x16x32_bf16(
                    af[mi], bfr[ni], acc[mi][ni], 0, 0, 0);
        __syncthreads();
    }
#undef KV_STAGE
    bool isK = (n0 < 1024);
#pragma unroll
    for (int ni = 0; ni < 4; ni++) {
        int col = n0 + wn + (ni << 4) + lq;
        if (isK) {
            int h = col >> 6, dc = (col >> 3) & 7, di = col & 7;
#pragma unroll
            for (int mi = 0; mi < 4; mi++)
#pragma unroll
                for (int r = 0; r < 4; r++) {
                    int row = m0 + wm + (mi << 4) + (quad << 2) + r;
                    int jg = row - rb;
                    int b = jg >> (10 - s);
                    int j = jg & (Ls - 1);
                    int bh = (b << 4) | h;
                    size_t addr = doff + (((size_t)bh * (Ls >> 4) + (j >> 4)) << 10) +
                                  (dc << 7) + ((j & 15) << 3) + di;
                    __builtin_nontemporal_store(f2bf(acc[mi][ni][r]), &kfrall[addr]);
                }
        } else {
#pragma unroll
            for (int mi = 0; mi < 4; mi++)
#pragma unroll
                for (int r = 0; r < 4; r++) {
                    int row = m0 + wm + (mi << 4) + (quad << 2) + r;
                    __builtin_nontemporal_store(f2bf(acc[mi][ni][r]),
                                                &kvall[(size_t)row * N + col]);
                }
        }
    }
}

// ---------------------------------------------------------------- split-K GEMM
// blockIdx.z selects K-slice; fp32 partials to Cout + z*M*N (nontemporal).
// Measured-best dbuf schedule.
__global__ __launch_bounds__(256) void mgemm_pk_kernel(
    const short* __restrict__ A, const short* __restrict__ Bt,
    const float* __restrict__ bias, float* __restrict__ Cout,
    int M, int N, int Kfull, int KH) {
    __shared__ short As[2][128 * 32];
    __shared__ short Bs[2][128 * 32];
    int kz = blockIdx.z;
    const short* Ab = A + (size_t)kz * KH;
    const short* Btb = Bt + (size_t)kz * KH;
    float* Co = Cout + (size_t)kz * M * N;
    int tid = threadIdx.x;
    int wave = tid >> 6, lane = tid & 63;
    int lq = lane & 15, quad = lane >> 4;
    int m0 = blockIdx.y << 7, n0 = blockIdx.x << 7;
    int wm = (wave & 1) << 6, wn = (wave >> 1) << 6;
    int r0 = tid >> 2, r1 = (256 + tid) >> 2;
    int kc0 = (tid & 3) << 3;
    const short* Ag0 = Ab + (size_t)(m0 + r0) * Kfull + kc0;
    const short* Ag1 = Ab + (size_t)(m0 + r1) * Kfull + kc0;
    const short* Bg0 = Btb + (size_t)(n0 + r0) * Kfull + kc0;
    const short* Bg1 = Btb + (size_t)(n0 + r1) * Kfull + kc0;
    float4v acc[4][4];
#pragma unroll
    for (int mi = 0; mi < 4; mi++)
#pragma unroll
        for (int ni = 0; ni < 4; ni++) acc[mi][ni] = (float4v){0.f, 0.f, 0.f, 0.f};

#define PK_STAGE(BUF, KO)                                                \
    {                                                                    \
        GLOAD_LDS16(Ag0 + (KO), As[BUF] + tid * 8);                      \
        GLOAD_LDS16(Ag1 + (KO), As[BUF] + (256 + tid) * 8);              \
        GLOAD_LDS16(Bg0 + (KO), Bs[BUF] + tid * 8);                      \
        GLOAD_LDS16(Bg1 + (KO), Bs[BUF] + (256 + tid) * 8);              \
    }
    int nk = KH >> 5;
    PK_STAGE(0, 0);
    __syncthreads();
    for (int t = 0; t < nk; t++) {
        int cur = t & 1;
        if (t + 1 < nk) PK_STAGE(cur ^ 1, (t + 1) << 5);
        short8 af[4], bfr[4];
#pragma unroll
        for (int mi = 0; mi < 4; mi++)
            af[mi] = *(const short8*)(As[cur] + ((wm + (mi << 4) + lq) << 5) + (quad << 3));
#pragma unroll
        for (int ni = 0; ni < 4; ni++)
            bfr[ni] = *(const short8*)(Bs[cur] + ((wn + (ni << 4) + lq) << 5) + (quad << 3));
#pragma unroll
        for (int mi = 0; mi < 4; mi++)
#pragma unroll
            for (int ni = 0; ni < 4; ni++)
                acc[mi][ni] = __builtin_amdgcn_mfma_f32_16x16x32_bf16(
                    af[mi], bfr[ni], acc[mi][ni], 0, 0, 0);
        __syncthreads();
    }
#undef PK_STAGE
#pragma unroll
    for (int ni = 0; ni < 4; ni++) {
        int col = n0 + wn + (ni << 4) + lq;
        float bv = (bias && kz == 0) ? bias[col] : 0.f;
#pragma unroll
        for (int mi = 0; mi < 4; mi++)
#pragma unroll
            for (int r = 0; r < 4; r++) {
                int row = m0 + wm + (mi << 4) + (quad << 2) + r;
                __builtin_nontemporal_store(acc[mi][ni][r] + bv,
                                            &Co[(size_t)row * N + col]);
            }
    }
}

// sum of 4 fp32 partial slabs -> bf16 (nt loads: read-once streams)
__global__ __launch_bounds__(256) void sumcast4_kernel(
    const float* __restrict__ p, size_t stride, short* __restrict__ outp) {
    int idx = (blockIdx.x * 256 + threadIdx.x) << 2;
    float4v a0 = __builtin_nontemporal_load((const float4v*)&p[idx]);
    float4v a1 = __builtin_nontemporal_load((const float4v*)&p[stride + idx]);
    float4v a2 = __builtin_nontemporal_load((const float4v*)&p[2 * stride + idx]);
    float4v a3 = __builtin_nontemporal_load((const float4v*)&p[3 * stride + idx]);
    ushort4 u;
    u.x = (unsigned short)f2bf(a0[0] + a1[0] + a2[0] + a3[0]);
    u.y = (unsigned short)f2bf(a0[1] + a1[1] + a2[1] + a3[1]);
    u.z = (unsigned short)f2bf(a0[2] + a1[2] + a2[2] + a3[2]);
    u.w = (unsigned short)f2bf(a0[3] + a1[3] + a2[3] + a3[3]);
    *(ushort4*)&outp[idx] = u;
}

// ---------------------------------------------------------------- conv tap-split
// Measured-best dbuf schedule.
__global__ __launch_bounds__(256) void convdil_pk_kernel(
    const short* __restrict__ xp, const short* __restrict__ Wt,
    float* __restrict__ pbuf) {
    __shared__ short As[2][128 * 32];
    __shared__ short Bs[2][128 * 32];
    int kp = blockIdx.z;
    int tid = threadIdx.x;
    int wave = tid >> 6, lane = tid & 63;
    int lq = lane & 15, quad = lane >> 4;
    int m0 = blockIdx.y << 7, n0 = blockIdx.x << 7;
    int wm = (wave & 1) << 6, wn = (wave >> 1) << 6;
    int b = m0 >> 10, ll0 = m0 & 1023;
    int r0 = tid >> 2, r1 = (256 + tid) >> 2;
    int kc = (tid & 3) << 3;
    float* Co = pbuf + (size_t)kp * DB * DL * DD;
    const short* Abase = xp + ((size_t)(b * 1028 + ll0 + 2 * kp)) * DD + kc;
    const short* Bbase = Wt + (size_t)kp * DD * DD;
    const short* Bg0 = Bbase + (size_t)(n0 + r0) * DD + kc;
    const short* Bg1 = Bbase + (size_t)(n0 + r1) * DD + kc;
    float4v acc[4][4];
#pragma unroll
    for (int mi = 0; mi < 4; mi++)
#pragma unroll
        for (int ni = 0; ni < 4; ni++) acc[mi][ni] = (float4v){0.f, 0.f, 0.f, 0.f};

#define CD_STAGE(BUF, KO)                                                        \
    {                                                                            \
        GLOAD_LDS16(Abase + (size_t)r0 * DD + (KO), As[BUF] + tid * 8);          \
        GLOAD_LDS16(Abase + (size_t)r1 * DD + (KO), As[BUF] + (256 + tid) * 8);  \
        GLOAD_LDS16(Bg0 + (KO), Bs[BUF] + tid * 8);                              \
        GLOAD_LDS16(Bg1 + (KO), Bs[BUF] + (256 + tid) * 8);                      \
    }
    int nk = DD >> 5;
    CD_STAGE(0, 0);
    __syncthreads();
    for (int t = 0; t < nk; t++) {
        int cur = t & 1;
        if (t + 1 < nk) CD_STAGE(cur ^ 1, (t + 1) << 5);
        short8 af[4], bfr[4];
#pragma unroll
        for (int mi = 0; mi < 4; mi++)
            af[mi] = *(const short8*)(As[cur] + ((wm + (mi << 4) + lq) << 5) + (quad << 3));
#pragma unroll
        for (int ni = 0; ni < 4; ni++)
            bfr[ni] = *(const short8*)(Bs[cur] + ((wn + (ni << 4) + lq) << 5) + (quad << 3));
#pragma unroll
        for (int mi = 0; mi < 4; mi++)
#pragma unroll
            for (int ni = 0; ni < 4; ni++)
                acc[mi][ni] = __builtin_amdgcn_mfma_f32_16x16x32_bf16(
                    af[mi], bfr[ni], acc[mi][ni], 0, 0, 0);
        __syncthreads();
    }
#undef CD_STAGE
#pragma unroll
    for (int ni = 0; ni < 4; ni++) {
        int col = n0 + wn + (ni << 4) + lq;
#pragma unroll
        for (int mi = 0; mi < 4; mi++)
#pragma unroll
            for (int r = 0; r < 4; r++) {
                int row = m0 + wm + (mi << 4) + (quad << 2) + r;
                __builtin_nontemporal_store(acc[mi][ni][r],
                                            &Co[(size_t)row * DD + col]);
            }
    }
}

// xcb = bf16(relu(p0+p1+p2 + bias)), 4 elems/thread over 4M
__global__ __launch_bounds__(256) void convcomb_kernel(
    const float* __restrict__ pbuf, const float* __restrict__ bvec,
    short* __restrict__ xcb) {
    const size_t M4 = (size_t)DB * DL * DD;
    int idx = (blockIdx.x * 256 + threadIdx.x) << 2;
    int col = idx & 1023;
    float4v p0 = __builtin_nontemporal_load((const float4v*)&pbuf[idx]);
    float4v p1 = __builtin_nontemporal_load((const float4v*)&pbuf[M4 + idx]);
    float4v p2 = __builtin_nontemporal_load((const float4v*)&pbuf[2 * M4 + idx]);
    float4v bb = *(const float4v*)&bvec[col];
    ushort4 u;
    u.x = (unsigned short)f2bf(fmaxf(p0[0] + p1[0] + p2[0] + bb[0], 0.f));
    u.y = (unsigned short)f2bf(fmaxf(p0[1] + p1[1] + p2[1] + bb[1], 0.f));
    u.z = (unsigned short)f2bf(fmaxf(p0[2] + p1[2] + p2[2] + bb[2], 0.f));
    u.w = (unsigned short)f2bf(fmaxf(p0[3] + p1[3] + p2[3] + bb[3], 0.f));
    *(ushort4*)&xcb[idx] = u;
}

// ---------------------------------------------------------------- V fragment prep
// k-axis within each 32-chunk PERMUTED to match the in-register P layout of the
// swapped-QK^T attention: slot m holds k-offset perm(m)=16*((m>>2)&1)+4*(m>>3)+(m&3).
// Within each (ks,t) 512-short block the element position is SLOT-GROUP-MAJOR:
// pos(slot,d) = (slot>>3)*128 + d*8 + (slot&7), so an attn lane (lq,quad) reads
// its 8 slots at byte offset quad*256+lq*16 — contiguous-1KB-per-wave,
// bank-conflict-free (global_load_lds staging can't pad).
__global__ __launch_bounds__(256) void vfrag_all_kernel(const short* __restrict__ kvall,
                                                        short* __restrict__ vfr0) {
    __shared__ short tile[32][33];
    int flat = blockIdx.x;                          // 0..7679
    int s, base, rb;
    size_t doff;
    if (flat < 4096)      { s = 0; base = 0;    rb = 0;    doff = 0; }
    else if (flat < 6144) { s = 1; base = 4096; rb = 4096; doff = 4194304; }
    else if (flat < 7168) { s = 2; base = 6144; rb = 6144; doff = 6291456; }
    else                  { s = 3; base = 7168; rb = 7168; doff = 7340032; }
    int rem = flat - base;
    int Ls = DL >> s;
    int nt = Ls >> 5;
    int j0t = rem & (nt - 1);
    int rest = rem >> (5 - s);
    int dt = rest & 1;
    int bh = rest >> 1;
    int j0 = j0t << 5, d0 = dt << 5;
    int b = bh >> 4, h = bh & 15;
    int tid = threadIdx.x;
    int cc = tid & 31, rr = tid >> 5;
#pragma unroll
    for (int p = 0; p < 4; p++) {
        int jj = (p << 3) + rr;
        tile[jj][cc] = kvall[((size_t)(rb + b * Ls + j0 + jj) << 11) + 1024 +
                             (h << 6) + d0 + cc];
    }
    __syncthreads();
    int c = j0 >> 6, ks = (j0 >> 5) & 1;
    int pc = (((cc >> 2) & 1) << 4) | ((cc >> 3) << 2) | (cc & 3);   // perm(cc)
#pragma unroll
    for (int p = 0; p < 4; p++) {
        int d = d0 + (p << 3) + rr;
        int tt = d >> 4, lqv = d & 15;
        size_t off = doff + (((size_t)bh * (Ls >> 6) + c) << 12) + (ks << 11) +
                     (tt << 9) + ((cc & 24) << 4) + (lqv << 3) + (cc & 7);
        vfr0[off] = tile[pc][(p << 3) + rr];
    }
}

// ---------------------------------------------------------------- attention
// In-register-P flash attention (swapped QK^T) with block-shared K/V staged
// through LDS (global_load_lds, double-buffered, one barrier per tile).
static __device__ __forceinline__ float fexp2(float x) {
    return __builtin_amdgcn_exp2f(x);
}

#define STAGE9(BUF, TILE)                                                         \
    {                                                                             \
        const short* _gs = (w < 2)                                                \
            ? kt + ((size_t)(TILE) << 12) + (w << 11) + (lane << 3)               \
            : vt + ((size_t)(TILE) << 12) + ((w - 2) << 11) + (lane << 3);        \
        short* _lb = sbuf[BUF] + (w << 11) + (lane << 3);                         \
        _Pragma("unroll") for (int _i = 0; _i < 4; _i++)                          \
            GLOAD_LDS16(_gs + (_i << 9), _lb + (_i << 9));                        \
    }

__global__ __launch_bounds__(256) void attn_fused9_kernel(
    const short* __restrict__ qb4, const short* __restrict__ kfr0,
    const short* __restrict__ vfr0, const float* __restrict__ wagg,
    short* __restrict__ attb) {
    __shared__ __align__(16) short sbuf[2][8192];   // 2 x 16 KB (K 8K | V 8K)
    int tid = threadIdx.x;
    int w = tid >> 6, lane = tid & 63;
    int lq = lane & 15, quad = lane >> 4;
    int bh = blockIdx.x;                 // XCD-local: id%8 == bh%8
    int b = bh >> 4, h = bh & 15;
    int qrow0 = b * DL + (blockIdx.y << 6) + (w << 4);
    const float c_exp = 0.18033688f;    // log2(e)/8
    int fo = (quad << 7) + (lq << 3);   // fragment byte offset/2 within region

    float fin[4][4];
#pragma unroll
    for (int t = 0; t < 4; t++)
#pragma unroll
        for (int r = 0; r < 4; r++) fin[t][r] = 0.f;

#pragma unroll 1
    for (int s = 0; s < 4; s++) {
        int Ls = DL >> s;
        size_t doff = s == 0 ? 0 : s == 1 ? 4194304 : s == 2 ? 6291456 : 7340032;

        const short* qbase = qb4 + ((size_t)(qrow0 + lq) << 12) + (s << 10) +
                             (h << 6) + (quad << 3);
        short8 qf0 = __builtin_nontemporal_load((const short8*)qbase);
        short8 qf1 = __builtin_nontemporal_load((const short8*)(qbase + 32));

        const short* kt = kfr0 + doff + (((size_t)bh * (Ls >> 4)) << 10);
        const short* vt = vfr0 + doff + (((size_t)bh * (Ls >> 6)) << 12);

        float4v O[4];
        float lsum = 0.f;
#pragma unroll
        for (int t = 0; t < 4; t++) O[t] = (float4v){0.f, 0.f, 0.f, 0.f};

        int nt = Ls >> 6;                // 16 / 8 / 4 / 2
        STAGE9(0, 0);
#pragma unroll 1
        for (int c = 0; c < nt; c++) {
            __syncthreads();             // stage(cur) complete; prev reads done
            int cur = c & 1;
            if (c + 1 < nt) STAGE9(cur ^ 1, c + 1);
            const short* kl = sbuf[cur] + fo;
            const short* vl = sbuf[cur] + 4096 + fo;

            float4v S[4];
#pragma unroll
            for (int t = 0; t < 4; t++) {
                short8 kf0 = *(const short8*)(kl + (t << 10));
                short8 kf1 = *(const short8*)(kl + (t << 10) + 512);
                float4v zz = (float4v){0.f, 0.f, 0.f, 0.f};
                zz = __builtin_amdgcn_mfma_f32_16x16x32_bf16(kf0, qf0, zz, 0, 0, 0);
                S[t] = __builtin_amdgcn_mfma_f32_16x16x32_bf16(kf1, qf1, zz, 0, 0, 0);
            }

            unsigned wpk[8];
#pragma unroll
            for (int t = 0; t < 4; t++) {
                float p0 = fexp2(S[t][0] * c_exp);
                float p1 = fexp2(S[t][1] * c_exp);
                float p2 = fexp2(S[t][2] * c_exp);
                float p3 = fexp2(S[t][3] * c_exp);
                lsum += p0 + p1 + p2 + p3;
                wpk[2 * t]     = (__float_as_uint(p1) & 0xFFFF0000u) |
                                 (__float_as_uint(p0) >> 16);
                wpk[2 * t + 1] = (__float_as_uint(p3) & 0xFFFF0000u) |
                                 (__float_as_uint(p2) >> 16);
            }
            union AFU { unsigned u[4]; short8 s8; };
            AFU af0, af1;
            af0.u[0] = wpk[0]; af0.u[1] = wpk[1]; af0.u[2] = wpk[2]; af0.u[3] = wpk[3];
            af1.u[0] = wpk[4]; af1.u[1] = wpk[5]; af1.u[2] = wpk[6]; af1.u[3] = wpk[7];
#pragma unroll
            for (int t = 0; t < 4; t++) {
                short8 vf = *(const short8*)(vl + (t << 9));
                O[t] = __builtin_amdgcn_mfma_f32_16x16x32_bf16(af0.s8, vf, O[t], 0, 0, 0);
            }
#pragma unroll
            for (int t = 0; t < 4; t++) {
                short8 vf = *(const short8*)(vl + 2048 + (t << 9));
                O[t] = __builtin_amdgcn_mfma_f32_16x16x32_bf16(af1.s8, vf, O[t], 0, 0, 0);
            }
        }
        __syncthreads();                 // all reads done before next scale stages

        // denominator: lane-local partial over 16 k's; reduce across quads
        lsum += __shfl_xor(lsum, 16, 64);
        lsum += __shfl_xor(lsum, 32, 64);
        // redistribute l[q] to O's row layout (q = quad*4+r) and accumulate
        float wsc = wagg[s];
#pragma unroll
        for (int r = 0; r < 4; r++) {
            int sl = (lane & 48) | (((lane >> 4) << 2) + r);
            float lr = __shfl(lsum, sl, 64);
            float linv = wsc / lr;
#pragma unroll
            for (int t = 0; t < 4; t++) fin[t][r] += O[t][r] * linv;
        }
    }
#pragma unroll
    for (int r = 0; r < 4; r++) {
        size_t rbase = ((size_t)(qrow0 + (quad << 2) + r) << 10) + (h << 6) + lq;
#pragma unroll
        for (int t = 0; t < 4; t++)
            __builtin_nontemporal_store(f2bf(fin[t][r]), &attb[rbase + (t << 4)]);
    }
}

// ---------------------------------------------------------------- add-N + LN
// out = LN(a + sum_j pb[j*pstride + .]); OBF: also write bf16 copy.
// Partial-slab reads are nontemporal (read-once streams).
template <int NP, int OBF>
__global__ __launch_bounds__(256) void addlnN_kernel(
    const float* __restrict__ a, const float* __restrict__ pb, size_t pstride,
    const float* __restrict__ gam, const float* __restrict__ bet,
    float* __restrict__ out, short* __restrict__ outb) {
    __shared__ float redA[4], redB[4];
    int row = blockIdx.x, tid = threadIdx.x;
    size_t base = (size_t)row * DD + (tid << 2);
    float4v av = *(const float4v*)&a[base];
    float s0 = av[0], s1 = av[1], s2 = av[2], s3 = av[3];
#pragma unroll
    for (int j = 0; j < NP; j++) {
        float4v pv = __builtin_nontemporal_load(
            (const float4v*)&pb[(size_t)j * pstride + base]);
        s0 += pv[0]; s1 += pv[1]; s2 += pv[2]; s3 += pv[3];
    }
    float lsum = s0 + s1 + s2 + s3;
    float lsq = s0 * s0 + s1 * s1 + s2 * s2 + s3 * s3;
#pragma unroll
    for (int o = 32; o > 0; o >>= 1) {
        lsum += __shfl_down(lsum, o, 64);
        lsq += __shfl_down(lsq, o, 64);
    }
    int lane = tid & 63, wid = tid >> 6;
    if (lane == 0) { redA[wid] = lsum; redB[wid] = lsq; }
    __syncthreads();
    float tsum = redA[0] + redA[1] + redA[2] + redA[3];
    float tsq = redB[0] + redB[1] + redB[2] + redB[3];
    float mean = tsum * (1.0f / DD);
    float var = tsq * (1.0f / DD) - mean * mean;
    float rstd = rsqrtf(var + 1e-5f);
    float4v gv = *(const float4v*)&gam[tid << 2];
    float4v bev = *(const float4v*)&bet[tid << 2];
    float4v o;
    o[0] = (s0 - mean) * rstd * gv[0] + bev[0];
    o[1] = (s1 - mean) * rstd * gv[1] + bev[1];
    o[2] = (s2 - mean) * rstd * gv[2] + bev[2];
    o[3] = (s3 - mean) * rstd * gv[3] + bev[3];
    *(float4v*)&out[base] = o;
    if (OBF) {
        ushort4 u;
        u.x = (unsigned short)f2bf(o[0]);
        u.y = (unsigned short)f2bf(o[1]);
        u.z = (unsigned short)f2bf(o[2]);
        u.w = (unsigned short)f2bf(o[3]);
        *(ushort4*)&outb[base] = u;
    }
}

// ---------------------------------------------------------------- launcher
extern "C" void kernel_launch(void* const* d_in, const int* in_sizes, int n_in,
                              void* d_out, int out_size, void* d_ws, size_t ws_size,
                              hipStream_t stream) {
    (void)in_sizes; (void)n_in; (void)out_size; (void)ws_size;
    const float* x   = (const float*)d_in[0];
    const float* Wdc = (const float*)d_in[1];
    const float* bdc = (const float*)d_in[2];
    const float* Wdec= (const float*)d_in[3];
    const float* Wq  = (const float*)d_in[4];
    const float* Wk  = (const float*)d_in[5];
    const float* Wv  = (const float*)d_in[6];
    const float* Wo  = (const float*)d_in[7];
    const float* agg = (const float*)d_in[8];
    const float* g1  = (const float*)d_in[9];
    const float* be1 = (const float*)d_in[10];
    const float* g2  = (const float*)d_in[11];
    const float* be2 = (const float*)d_in[12];
    const float* W1  = (const float*)d_in[13];
    const float* b1  = (const float*)d_in[14];
    const float* W2  = (const float*)d_in[15];
    const float* b2  = (const float*)d_in[16];
    float* out = (float*)d_out;

    float* ws = (float*)d_ws;
    size_t off = 0;
    auto alloc = [&](size_t nfloats) { float* p = ws + off; off += nfloats; return p; };
    const size_t M1 = 1024 * 1024;
    short* wdc_bt  = (short*)alloc(3 * M1 / 2);
    short* wdec_bt = (short*)alloc(3 * M1);
    short* wq4t    = (short*)alloc(2 * M1);
    short* wkvt    = (short*)alloc(4 * M1);
    short* wot     = (short*)alloc(M1 / 2);
    short* w1t     = (short*)alloc(2 * M1);
    short* w2t     = (short*)alloc(2 * M1);
    float* wagg    = alloc(64);
    short* xpad    = (short*)alloc(2105344);
    // activation buffers: contiguous rows 0..7679 for grouped KV GEMM
    short* xcb     = (short*)alloc(2 * M1);         // rows [0,4096)
    short* s1b     = (short*)alloc(M1);             // rows [4096,6144)
    short* s2b     = (short*)alloc(M1 / 2);         // rows [6144,7168)
    short* s3b     = (short*)alloc(M1 / 4);         // rows [7168,7680)
    short* qb4     = (short*)alloc(8 * M1);         // later FFN hidden; conv partials first
    short* kvall   = (short*)alloc(7 * M1 + M1 / 2);// V-half rows; FFN2 partials later
    short* kfrall  = (short*)alloc(3 * M1 + 3 * M1 / 4);
    short* vfrall  = (short*)alloc(3 * M1 + 3 * M1 / 4);
    short* attb    = (short*)alloc(2 * M1);
    float* x1      = alloc(4 * M1);
    short* x1b     = (short*)alloc(2 * M1);
    float* pkbuf   = alloc(8 * M1);                 // Wo/dec split-K partials
    short* hb      = qb4;                           // FFN hidden [4096][4096] bf16
    float* convp   = (float*)qb4;                   // conv tap partials (12M fp32:
                                                    //  qb4 8M + kvall first 4M, contiguous)
    float* pk4     = (float*)kvall;                 // FFN2 2x4M fp32 partials
                                                    //  (kvall region; dead after attention)

    dim3 blk(256);
    // ---- fused prep
    prep_all_kernel<<<dim3(74817), blk, 0, stream>>>(
        Wdc, Wdec, Wq, Wk, Wv, Wo, W1, W2, x, agg,
        wdc_bt, wdec_bt, wq4t, wkvt, wot, w1t, w2t, xpad, wagg,
        out + (size_t)DB * DL * DD);

    // 1. dilated conv: tap-split x3 + relu/bias combine
    convdil_pk_kernel<<<dim3(DD / 128, DB * DL / 128, 3), blk, 0, stream>>>(
        xpad, wdc_bt, convp);
    convcomb_kernel<<<dim3(4 * M1 / (256 * 4)), blk, 0, stream>>>(convp, bdc, xcb);

    // 2. decomposition convs: split-K x4 each (512/256/128 blocks) + sum-cast
    mgemm_pk_kernel<<<dim3(8, 16, 4), blk, 0, stream>>>(
        xcb, wdec_bt, nullptr, pkbuf, 2048, DD, 2 * DD, 512);
    sumcast4_kernel<<<dim3(2 * M1 / 1024), blk, 0, stream>>>(pkbuf, 2 * M1, s1b);
    mgemm_pk_kernel<<<dim3(8, 8, 4), blk, 0, stream>>>(
        s1b, wdec_bt + 2 * M1, nullptr, pkbuf, 1024, DD, 2 * DD, 512);
    sumcast4_kernel<<<dim3(M1 / 1024), blk, 0, stream>>>(pkbuf, M1, s2b);
    mgemm_pk_kernel<<<dim3(8, 4, 4), blk, 0, stream>>>(
        s2b, wdec_bt + 4 * M1, nullptr, pkbuf, 512, DD, 2 * DD, 512);
    sumcast4_kernel<<<dim3(M1 / 2048), blk, 0, stream>>>(pkbuf, M1 / 2, s3b);

    // 3a. batched Q projection (all 4 scales, N=4096)
    mgemm_kernel<0, 1><<<dim3(32, 32), blk, 0, stream>>>(
        xcb, wq4t, nullptr, qb4, DB * DL, 4 * DD, DD);

    // 3b. grouped K|V projection (K-half straight to fragment layout)
    kvgemm_kernel<<<dim3(16, 60), blk, 0, stream>>>(xcb, wkvt, kvall, kfrall);

    // 3c. V fragment prep (k-permuted, slot-group-major for LDS staging)
    vfrag_all_kernel<<<dim3(7680), blk, 0, stream>>>(kvall, vfrall);

    // 3d. fused attention, block-shared K/V via LDS double-buffer,
    //     in-register P, XCD-locality swizzled
    attn_fused9_kernel<<<dim3(DB * DH, DL / 64), blk, 0, stream>>>(
        qb4, kfrall, vfrall, wagg, attb);

    // 4. shared output projection (split-K x2)
    mgemm_pk_kernel<<<dim3(8, 32, 2), blk, 0, stream>>>(
        attb, wot, nullptr, pkbuf, DB * DL, DD, DD, DD / 2);

    // 5. residual + LN1 (2 partials)
    addlnN_kernel<2, 1><<<dim3(DB * DL), blk, 0, stream>>>(
        x, pkbuf, 4 * M1, g1, be1, x1, x1b);

    // 6. FFN: GELU GEMM then split-K x2 down-projection (512 blocks; halves
    //    the fp32 partial round-trip vs x4)
    mgemm_kernel<1, 1><<<dim3(DF / 128, (DB * DL) / 128), blk, 0, stream>>>(
        x1b, w1t, b1, hb, DB * DL, DF, DD);
    mgemm_pk_kernel<<<dim3(8, 32, 2), blk, 0, stream>>>(
        hb, w2t, b2, pk4, DB * DL, DD, DF, DF / 2);

    // 7. residual + LN2 -> out (2 partials)
    addlnN_kernel<2, 0><<<dim3(DB * DL), blk, 0, stream>>>(
        x1, pk4, 4 * M1, g2, be2, out, nullptr);
}

// Round 11
// 667.445 us; speedup vs baseline: 1.0553x; 1.0553x over previous
//
#include <hip/hip_runtime.h>
#include <cstddef>

#define DB 4
#define DL 1024
#define DD 1024
#define DH 16
#define DF 4096

typedef __attribute__((ext_vector_type(8))) short short8;
typedef __attribute__((ext_vector_type(4))) float float4v;

static __device__ __forceinline__ short f2bf(float f) {
    unsigned u = __float_as_uint(f);
    unsigned r = (u + 0x7FFFu + ((u >> 16) & 1u)) >> 16;   // RNE
    return (short)r;
}

#define GLOAD_LDS16(gp, lp)                                                          \
    __builtin_amdgcn_global_load_lds(                                                \
        (const __attribute__((address_space(1))) void*)(gp),                         \
        (__attribute__((address_space(3))) void*)(lp), 16, 0, 0)

// ---------------------------------------------------------------- mega-prep
__global__ __launch_bounds__(256) void prep_all_kernel(
    const float* __restrict__ Wdc, const float* __restrict__ Wdec,
    const float* __restrict__ Wq, const float* __restrict__ Wk,
    const float* __restrict__ Wv, const float* __restrict__ Wo,
    const float* __restrict__ W1, const float* __restrict__ W2,
    const float* __restrict__ x, const float* __restrict__ agg,
    short* __restrict__ wdc_bt, short* __restrict__ wdec_bt,
    short* __restrict__ wq4t, short* __restrict__ wkvt, short* __restrict__ wot,
    short* __restrict__ w1t, short* __restrict__ w2t, short* __restrict__ xpad,
    float* __restrict__ wagg, float* __restrict__ aux) {
    __shared__ float tile[32][33];
    const size_t M1 = 1024 * 1024;
    int blk = blockIdx.x, tid = threadIdx.x;
    if (blk < 12288) {
        int idx = blk * 256 + tid;
        int i = idx & 1023, o = (idx >> 10) & 1023, k = idx >> 20;
        wdc_bt[idx] = f2bf(Wdc[((size_t)o * 1024 + i) * 3 + k]);
        return;
    }
    if (blk < 36864) {
        int idx = (blk - 12288) * 256 + tid;
        int i = idx & 1023, k2 = (idx >> 10) & 1, n = (idx >> 11) & 1023, s = idx >> 21;
        wdec_bt[idx] = f2bf(Wdec[(((size_t)(s * 1024 + n)) * 1024 + i) * 2 + k2]);
        return;
    }
    if (blk < 58368) {
        const float* src; short* dst; int K, N, bx, by;
        if (blk < 50176) {
            int r = blk - 36864;
            int z = r >> 10, rem = r & 1023;
            bx = rem & 31; by = rem >> 5; K = 1024; N = 1024;
            if (z < 4)      { src = Wq + (size_t)z * M1;       dst = wq4t + (size_t)z * M1; }
            else if (z < 8) { src = Wk + (size_t)(z - 4) * M1; dst = wkvt + (size_t)(z - 4) * 2 * M1; }
            else if (z < 12){ src = Wv;                        dst = wkvt + (size_t)(z - 8) * 2 * M1 + M1; }
            else            { src = Wo;                        dst = wot; }
        } else if (blk < 54272) {
            int r = blk - 50176;
            bx = r & 127; by = r >> 7; K = 1024; N = 4096; src = W1; dst = w1t;
        } else {
            int r = blk - 54272;
            bx = r & 31; by = r >> 5; K = 4096; N = 1024; src = W2; dst = w2t;
        }
        int n0 = bx << 5, k0 = by << 5;
        int cc = tid & 31, rr = tid >> 5;
#pragma unroll
        for (int p = 0; p < 4; p++) {
            int kk = (p << 3) + rr;
            tile[kk][cc] = src[(size_t)(k0 + kk) * N + n0 + cc];
        }
        __syncthreads();
#pragma unroll
        for (int p = 0; p < 4; p++) {
            int nn = (p << 3) + rr;
            dst[(size_t)(n0 + nn) * K + k0 + cc] = f2bf(tile[cc][nn]);
        }
        return;
    }
    if (blk < 74816) {
        int idx = (blk - 58368) * 256 + tid;
        int d = idx & 1023;
        int row = (idx >> 10) % 1028;
        int b = (idx >> 10) / 1028;
        int l = row - 2;
        float v = (l >= 0 && l < DL) ? x[((size_t)(b * DL + l)) * DD + d] : 0.f;
        xpad[idx] = f2bf(v);
        return;
    }
    if (tid == 0) {
        float l0 = agg[0], l1 = agg[1], l2 = agg[2], l3 = agg[3];
        float m = fmaxf(fmaxf(l0, l1), fmaxf(l2, l3));
        float e0 = __expf(l0 - m), e1 = __expf(l1 - m);
        float e2 = __expf(l2 - m), e3 = __expf(l3 - m);
        float ssum = e0 + e1 + e2 + e3;
        float w0 = e0 / ssum, w1 = e1 / ssum, w2 = e2 / ssum, w3 = e3 / ssum;
        wagg[0] = w0; wagg[1] = w1; wagg[2] = w2; wagg[3] = w3;
        *aux = -(w0 * logf(w0 + 1e-9f) + w1 * logf(w1 + 1e-9f) +
                 w2 * logf(w2 + 1e-9f) + w3 * logf(w3 + 1e-9f));
    }
}

// ---------------------------------------------------------------- MFMA GEMM
// Measured-best schedule: double-buffered LDS; tile t+1's global_load_lds
// issued at step TOP, single __syncthreads() at step BOTTOM. Regular epilogue
// stores (nt on 2B bf16 stores measured WORSE: bypasses L2 write-combining ->
// partial-line HBM writes; keep nt only for full-line fp32 partial streams).
template <int ACT, int OBF>
__global__ __launch_bounds__(256) void mgemm_kernel(
    const short* __restrict__ A, const short* __restrict__ Bt,
    const float* __restrict__ bias, void* __restrict__ Cv,
    int M, int N, int K) {
    __shared__ short As[2][128 * 32];
    __shared__ short Bs[2][128 * 32];
    int tid = threadIdx.x;
    int wave = tid >> 6, lane = tid & 63;
    int lq = lane & 15, quad = lane >> 4;
    int m0 = blockIdx.y << 7, n0 = blockIdx.x << 7;
    int wm = (wave & 1) << 6, wn = (wave >> 1) << 6;
    int r0 = tid >> 2, r1 = (256 + tid) >> 2;
    int kc0 = (tid & 3) << 3;
    const short* Ag0 = A + (size_t)(m0 + r0) * K + kc0;
    const short* Ag1 = A + (size_t)(m0 + r1) * K + kc0;
    const short* Bg0 = Bt + (size_t)(n0 + r0) * K + kc0;
    const short* Bg1 = Bt + (size_t)(n0 + r1) * K + kc0;
    float4v acc[4][4];
#pragma unroll
    for (int mi = 0; mi < 4; mi++)
#pragma unroll
        for (int ni = 0; ni < 4; ni++) acc[mi][ni] = (float4v){0.f, 0.f, 0.f, 0.f};

#define MG_STAGE(BUF, KO)                                                \
    {                                                                    \
        GLOAD_LDS16(Ag0 + (KO), As[BUF] + tid * 8);                      \
        GLOAD_LDS16(Ag1 + (KO), As[BUF] + (256 + tid) * 8);              \
        GLOAD_LDS16(Bg0 + (KO), Bs[BUF] + tid * 8);                      \
        GLOAD_LDS16(Bg1 + (KO), Bs[BUF] + (256 + tid) * 8);              \
    }
    int nk = K >> 5;
    MG_STAGE(0, 0);
    __syncthreads();
    for (int t = 0; t < nk; t++) {
        int cur = t & 1;
        if (t + 1 < nk) MG_STAGE(cur ^ 1, (t + 1) << 5);
        short8 af[4], bfr[4];
#pragma unroll
        for (int mi = 0; mi < 4; mi++)
            af[mi] = *(const short8*)(As[cur] + ((wm + (mi << 4) + lq) << 5) + (quad << 3));
#pragma unroll
        for (int ni = 0; ni < 4; ni++)
            bfr[ni] = *(const short8*)(Bs[cur] + ((wn + (ni << 4) + lq) << 5) + (quad << 3));
#pragma unroll
        for (int mi = 0; mi < 4; mi++)
#pragma unroll
            for (int ni = 0; ni < 4; ni++)
                acc[mi][ni] = __builtin_amdgcn_mfma_f32_16x16x32_bf16(
                    af[mi], bfr[ni], acc[mi][ni], 0, 0, 0);
        __syncthreads();
    }
#undef MG_STAGE
#pragma unroll
    for (int ni = 0; ni < 4; ni++) {
        int col = n0 + wn + (ni << 4) + lq;
        float bv = bias ? bias[col] : 0.f;
#pragma unroll
        for (int mi = 0; mi < 4; mi++) {
#pragma unroll
            for (int r = 0; r < 4; r++) {
                int row = m0 + wm + (mi << 4) + (quad << 2) + r;
                float v = acc[mi][ni][r] + bv;
                if (ACT == 1) v = 0.5f * v * (1.0f + erff(v * 0.70710678118654752f));
                if (OBF) ((short*)Cv)[(size_t)row * N + col] = f2bf(v);
                else ((float*)Cv)[(size_t)row * N + col] = v;
            }
        }
    }
}

// ---------------------------------------------------------------- grouped KV GEMM
// K-half columns written directly in K-fragment layout; V-half row-major.
// Same measured-best dbuf schedule.
__global__ __launch_bounds__(256) void kvgemm_kernel(
    const short* __restrict__ acts, const short* __restrict__ wkvt,
    short* __restrict__ kvall, short* __restrict__ kfrall) {
    __shared__ short As[2][128 * 32];
    __shared__ short Bs[2][128 * 32];
    int my = blockIdx.y;                       // 0..59
    int s = my < 32 ? 0 : my < 48 ? 1 : my < 56 ? 2 : 3;
    int m0 = my << 7;
    int rb = s == 0 ? 0 : s == 1 ? 4096 : s == 2 ? 6144 : 7168;
    size_t doff = s == 0 ? 0 : s == 1 ? 4194304 : s == 2 ? 6291456 : 7340032;
    int Ls = DL >> s;
    const short* Bt = wkvt + (size_t)s * 2097152;
    const int K = 1024, N = 2048;
    int tid = threadIdx.x;
    int wave = tid >> 6, lane = tid & 63;
    int lq = lane & 15, quad = lane >> 4;
    int n0 = blockIdx.x << 7;
    int wm = (wave & 1) << 6, wn = (wave >> 1) << 6;
    int r0 = tid >> 2, r1 = (256 + tid) >> 2;
    int kc0 = (tid & 3) << 3;
    const short* Ag0 = acts + (size_t)(m0 + r0) * K + kc0;
    const short* Ag1 = acts + (size_t)(m0 + r1) * K + kc0;
    const short* Bg0 = Bt + (size_t)(n0 + r0) * K + kc0;
    const short* Bg1 = Bt + (size_t)(n0 + r1) * K + kc0;
    float4v acc[4][4];
#pragma unroll
    for (int mi = 0; mi < 4; mi++)
#pragma unroll
        for (int ni = 0; ni < 4; ni++) acc[mi][ni] = (float4v){0.f, 0.f, 0.f, 0.f};

#define KV_STAGE(BUF, KO)                                                \
    {                                                                    \
        GLOAD_LDS16(Ag0 + (KO), As[BUF] + tid * 8);                      \
        GLOAD_LDS16(Ag1 + (KO), As[BUF] + (256 + tid) * 8);              \
        GLOAD_LDS16(Bg0 + (KO), Bs[BUF] + tid * 8);                      \
        GLOAD_LDS16(Bg1 + (KO), Bs[BUF] + (256 + tid) * 8);              \
    }
    int nk = K >> 5;
    KV_STAGE(0, 0);
    __syncthreads();
    for (int t = 0; t < nk; t++) {
        int cur = t & 1;
        if (t + 1 < nk) KV_STAGE(cur ^ 1, (t + 1) << 5);
        short8 af[4], bfr[4];
#pragma unroll
        for (int mi = 0; mi < 4; mi++)
            af[mi] = *(const short8*)(As[cur] + ((wm + (mi << 4) + lq) << 5) + (quad << 3));
#pragma unroll
        for (int ni = 0; ni < 4; ni++)
            bfr[ni] = *(const short8*)(Bs[cur] + ((wn + (ni << 4) + lq) << 5) + (quad << 3));
#pragma unroll
        for (int mi = 0; mi < 4; mi++)
#pragma unroll
            for (int ni = 0; ni < 4; ni++)
                acc[mi][ni] = __builtin_amdgcn_mfma_f32_16x16x32_bf16(
                    af[mi], bfr[ni], acc[mi][ni], 0, 0, 0);
        __syncthreads();
    }
#undef KV_STAGE
    bool isK = (n0 < 1024);
#pragma unroll
    for (int ni = 0; ni < 4; ni++) {
        int col = n0 + wn + (ni << 4) + lq;
        if (isK) {
            int h = col >> 6, dc = (col >> 3) & 7, di = col & 7;
#pragma unroll
            for (int mi = 0; mi < 4; mi++)
#pragma unroll
                for (int r = 0; r < 4; r++) {
                    int row = m0 + wm + (mi << 4) + (quad << 2) + r;
                    int jg = row - rb;
                    int b = jg >> (10 - s);
                    int j = jg & (Ls - 1);
                    int bh = (b << 4) | h;
                    size_t addr = doff + (((size_t)bh * (Ls >> 4) + (j >> 4)) << 10) +
                                  (dc << 7) + ((j & 15) << 3) + di;
                    kfrall[addr] = f2bf(acc[mi][ni][r]);
                }
        } else {
#pragma unroll
            for (int mi = 0; mi < 4; mi++)
#pragma unroll
                for (int r = 0; r < 4; r++) {
                    int row = m0 + wm + (mi << 4) + (quad << 2) + r;
                    kvall[(size_t)row * N + col] = f2bf(acc[mi][ni][r]);
                }
        }
    }
}

// ---------------------------------------------------------------- split-K GEMM
// blockIdx.z selects K-slice; fp32 partials to Cout + z*M*N (nontemporal —
// full-line fp32 streams, written once / read once; measured win).
__global__ __launch_bounds__(256) void mgemm_pk_kernel(
    const short* __restrict__ A, const short* __restrict__ Bt,
    const float* __restrict__ bias, float* __restrict__ Cout,
    int M, int N, int Kfull, int KH) {
    __shared__ short As[2][128 * 32];
    __shared__ short Bs[2][128 * 32];
    int kz = blockIdx.z;
    const short* Ab = A + (size_t)kz * KH;
    const short* Btb = Bt + (size_t)kz * KH;
    float* Co = Cout + (size_t)kz * M * N;
    int tid = threadIdx.x;
    int wave = tid >> 6, lane = tid & 63;
    int lq = lane & 15, quad = lane >> 4;
    int m0 = blockIdx.y << 7, n0 = blockIdx.x << 7;
    int wm = (wave & 1) << 6, wn = (wave >> 1) << 6;
    int r0 = tid >> 2, r1 = (256 + tid) >> 2;
    int kc0 = (tid & 3) << 3;
    const short* Ag0 = Ab + (size_t)(m0 + r0) * Kfull + kc0;
    const short* Ag1 = Ab + (size_t)(m0 + r1) * Kfull + kc0;
    const short* Bg0 = Btb + (size_t)(n0 + r0) * Kfull + kc0;
    const short* Bg1 = Btb + (size_t)(n0 + r1) * Kfull + kc0;
    float4v acc[4][4];
#pragma unroll
    for (int mi = 0; mi < 4; mi++)
#pragma unroll
        for (int ni = 0; ni < 4; ni++) acc[mi][ni] = (float4v){0.f, 0.f, 0.f, 0.f};

#define PK_STAGE(BUF, KO)                                                \
    {                                                                    \
        GLOAD_LDS16(Ag0 + (KO), As[BUF] + tid * 8);                      \
        GLOAD_LDS16(Ag1 + (KO), As[BUF] + (256 + tid) * 8);              \
        GLOAD_LDS16(Bg0 + (KO), Bs[BUF] + tid * 8);                      \
        GLOAD_LDS16(Bg1 + (KO), Bs[BUF] + (256 + tid) * 8);              \
    }
    int nk = KH >> 5;
    PK_STAGE(0, 0);
    __syncthreads();
    for (int t = 0; t < nk; t++) {
        int cur = t & 1;
        if (t + 1 < nk) PK_STAGE(cur ^ 1, (t + 1) << 5);
        short8 af[4], bfr[4];
#pragma unroll
        for (int mi = 0; mi < 4; mi++)
            af[mi] = *(const short8*)(As[cur] + ((wm + (mi << 4) + lq) << 5) + (quad << 3));
#pragma unroll
        for (int ni = 0; ni < 4; ni++)
            bfr[ni] = *(const short8*)(Bs[cur] + ((wn + (ni << 4) + lq) << 5) + (quad << 3));
#pragma unroll
        for (int mi = 0; mi < 4; mi++)
#pragma unroll
            for (int ni = 0; ni < 4; ni++)
                acc[mi][ni] = __builtin_amdgcn_mfma_f32_16x16x32_bf16(
                    af[mi], bfr[ni], acc[mi][ni], 0, 0, 0);
        __syncthreads();
    }
#undef PK_STAGE
#pragma unroll
    for (int ni = 0; ni < 4; ni++) {
        int col = n0 + wn + (ni << 4) + lq;
        float bv = (bias && kz == 0) ? bias[col] : 0.f;
#pragma unroll
        for (int mi = 0; mi < 4; mi++)
#pragma unroll
            for (int r = 0; r < 4; r++) {
                int row = m0 + wm + (mi << 4) + (quad << 2) + r;
                __builtin_nontemporal_store(acc[mi][ni][r] + bv,
                                            &Co[(size_t)row * N + col]);
            }
    }
}

// sum of 4 fp32 partial slabs -> bf16 (nt loads: read-once streams)
__global__ __launch_bounds__(256) void sumcast4_kernel(
    const float* __restrict__ p, size_t stride, short* __restrict__ outp) {
    int idx = (blockIdx.x * 256 + threadIdx.x) << 2;
    float4v a0 = __builtin_nontemporal_load((const float4v*)&p[idx]);
    float4v a1 = __builtin_nontemporal_load((const float4v*)&p[stride + idx]);
    float4v a2 = __builtin_nontemporal_load((const float4v*)&p[2 * stride + idx]);
    float4v a3 = __builtin_nontemporal_load((const float4v*)&p[3 * stride + idx]);
    ushort4 u;
    u.x = (unsigned short)f2bf(a0[0] + a1[0] + a2[0] + a3[0]);
    u.y = (unsigned short)f2bf(a0[1] + a1[1] + a2[1] + a3[1]);
    u.z = (unsigned short)f2bf(a0[2] + a1[2] + a2[2] + a3[2]);
    u.w = (unsigned short)f2bf(a0[3] + a1[3] + a2[3] + a3[3]);
    *(ushort4*)&outp[idx] = u;
}

// ---------------------------------------------------------------- conv tap-split
// Measured-best dbuf schedule; nt fp32 partial stores.
__global__ __launch_bounds__(256) void convdil_pk_kernel(
    const short* __restrict__ xp, const short* __restrict__ Wt,
    float* __restrict__ pbuf) {
    __shared__ short As[2][128 * 32];
    __shared__ short Bs[2][128 * 32];
    int kp = blockIdx.z;
    int tid = threadIdx.x;
    int wave = tid >> 6, lane = tid & 63;
    int lq = lane & 15, quad = lane >> 4;
    int m0 = blockIdx.y << 7, n0 = blockIdx.x << 7;
    int wm = (wave & 1) << 6, wn = (wave >> 1) << 6;
    int b = m0 >> 10, ll0 = m0 & 1023;
    int r0 = tid >> 2, r1 = (256 + tid) >> 2;
    int kc = (tid & 3) << 3;
    float* Co = pbuf + (size_t)kp * DB * DL * DD;
    const short* Abase = xp + ((size_t)(b * 1028 + ll0 + 2 * kp)) * DD + kc;
    const short* Bbase = Wt + (size_t)kp * DD * DD;
    const short* Bg0 = Bbase + (size_t)(n0 + r0) * DD + kc;
    const short* Bg1 = Bbase + (size_t)(n0 + r1) * DD + kc;
    float4v acc[4][4];
#pragma unroll
    for (int mi = 0; mi < 4; mi++)
#pragma unroll
        for (int ni = 0; ni < 4; ni++) acc[mi][ni] = (float4v){0.f, 0.f, 0.f, 0.f};

#define CD_STAGE(BUF, KO)                                                        \
    {                                                                            \
        GLOAD_LDS16(Abase + (size_t)r0 * DD + (KO), As[BUF] + tid * 8);          \
        GLOAD_LDS16(Abase + (size_t)r1 * DD + (KO), As[BUF] + (256 + tid) * 8);  \
        GLOAD_LDS16(Bg0 + (KO), Bs[BUF] + tid * 8);                              \
        GLOAD_LDS16(Bg1 + (KO), Bs[BUF] + (256 + tid) * 8);                      \
    }
    int nk = DD >> 5;
    CD_STAGE(0, 0);
    __syncthreads();
    for (int t = 0; t < nk; t++) {
        int cur = t & 1;
        if (t + 1 < nk) CD_STAGE(cur ^ 1, (t + 1) << 5);
        short8 af[4], bfr[4];
#pragma unroll
        for (int mi = 0; mi < 4; mi++)
            af[mi] = *(const short8*)(As[cur] + ((wm + (mi << 4) + lq) << 5) + (quad << 3));
#pragma unroll
        for (int ni = 0; ni < 4; ni++)
            bfr[ni] = *(const short8*)(Bs[cur] + ((wn + (ni << 4) + lq) << 5) + (quad << 3));
#pragma unroll
        for (int mi = 0; mi < 4; mi++)
#pragma unroll
            for (int ni = 0; ni < 4; ni++)
                acc[mi][ni] = __builtin_amdgcn_mfma_f32_16x16x32_bf16(
                    af[mi], bfr[ni], acc[mi][ni], 0, 0, 0);
        __syncthreads();
    }
#undef CD_STAGE
#pragma unroll
    for (int ni = 0; ni < 4; ni++) {
        int col = n0 + wn + (ni << 4) + lq;
#pragma unroll
        for (int mi = 0; mi < 4; mi++)
#pragma unroll
            for (int r = 0; r < 4; r++) {
                int row = m0 + wm + (mi << 4) + (quad << 2) + r;
                __builtin_nontemporal_store(acc[mi][ni][r],
                                            &Co[(size_t)row * DD + col]);
            }
    }
}

// xcb = bf16(relu(p0+p1+p2 + bias)), 4 elems/thread over 4M
__global__ __launch_bounds__(256) void convcomb_kernel(
    const float* __restrict__ pbuf, const float* __restrict__ bvec,
    short* __restrict__ xcb) {
    const size_t M4 = (size_t)DB * DL * DD;
    int idx = (blockIdx.x * 256 + threadIdx.x) << 2;
    int col = idx & 1023;
    float4v p0 = __builtin_nontemporal_load((const float4v*)&pbuf[idx]);
    float4v p1 = __builtin_nontemporal_load((const float4v*)&pbuf[M4 + idx]);
    float4v p2 = __builtin_nontemporal_load((const float4v*)&pbuf[2 * M4 + idx]);
    float4v bb = *(const float4v*)&bvec[col];
    ushort4 u;
    u.x = (unsigned short)f2bf(fmaxf(p0[0] + p1[0] + p2[0] + bb[0], 0.f));
    u.y = (unsigned short)f2bf(fmaxf(p0[1] + p1[1] + p2[1] + bb[1], 0.f));
    u.z = (unsigned short)f2bf(fmaxf(p0[2] + p1[2] + p2[2] + bb[2], 0.f));
    u.w = (unsigned short)f2bf(fmaxf(p0[3] + p1[3] + p2[3] + bb[3], 0.f));
    *(ushort4*)&xcb[idx] = u;
}

// ---------------------------------------------------------------- V fragment prep
// k-axis within each 32-chunk PERMUTED to match the in-register P layout of the
// swapped-QK^T attention: slot m holds k-offset perm(m)=16*((m>>2)&1)+4*(m>>3)+(m&3).
// Within each (ks,t) 512-short block the element position is SLOT-GROUP-MAJOR:
// pos(slot,d) = (slot>>3)*128 + d*8 + (slot&7), so an attn lane (lq,quad) reads
// its 8 slots at byte offset quad*256+lq*16 — contiguous-1KB-per-wave,
// bank-conflict-free (global_load_lds staging can't pad).
__global__ __launch_bounds__(256) void vfrag_all_kernel(const short* __restrict__ kvall,
                                                        short* __restrict__ vfr0) {
    __shared__ short tile[32][33];
    int flat = blockIdx.x;                          // 0..7679
    int s, base, rb;
    size_t doff;
    if (flat < 4096)      { s = 0; base = 0;    rb = 0;    doff = 0; }
    else if (flat < 6144) { s = 1; base = 4096; rb = 4096; doff = 4194304; }
    else if (flat < 7168) { s = 2; base = 6144; rb = 6144; doff = 6291456; }
    else                  { s = 3; base = 7168; rb = 7168; doff = 7340032; }
    int rem = flat - base;
    int Ls = DL >> s;
    int nt = Ls >> 5;
    int j0t = rem & (nt - 1);
    int rest = rem >> (5 - s);
    int dt = rest & 1;
    int bh = rest >> 1;
    int j0 = j0t << 5, d0 = dt << 5;
    int b = bh >> 4, h = bh & 15;
    int tid = threadIdx.x;
    int cc = tid & 31, rr = tid >> 5;
#pragma unroll
    for (int p = 0; p < 4; p++) {
        int jj = (p << 3) + rr;
        tile[jj][cc] = kvall[((size_t)(rb + b * Ls + j0 + jj) << 11) + 1024 +
                             (h << 6) + d0 + cc];
    }
    __syncthreads();
    int c = j0 >> 6, ks = (j0 >> 5) & 1;
    int pc = (((cc >> 2) & 1) << 4) | ((cc >> 3) << 2) | (cc & 3);   // perm(cc)
#pragma unroll
    for (int p = 0; p < 4; p++) {
        int d = d0 + (p << 3) + rr;
        int tt = d >> 4, lqv = d & 15;
        size_t off = doff + (((size_t)bh * (Ls >> 6) + c) << 12) + (ks << 11) +
                     (tt << 9) + ((cc & 24) << 4) + (lqv << 3) + (cc & 7);
        vfr0[off] = tile[pc][(p << 3) + rr];
    }
}

// ---------------------------------------------------------------- attention
// In-register-P flash attention (swapped QK^T) with block-shared K/V staged
// through LDS (global_load_lds, double-buffered, one barrier per tile).
static __device__ __forceinline__ float fexp2(float x) {
    return __builtin_amdgcn_exp2f(x);
}

#define STAGE9(BUF, TILE)                                                         \
    {                                                                             \
        const short* _gs = (w < 2)                                                \
            ? kt + ((size_t)(TILE) << 12) + (w << 11) + (lane << 3)               \
            : vt + ((size_t)(TILE) << 12) + ((w - 2) << 11) + (lane << 3);        \
        short* _lb = sbuf[BUF] + (w << 11) + (lane << 3);                         \
        _Pragma("unroll") for (int _i = 0; _i < 4; _i++)                          \
            GLOAD_LDS16(_gs + (_i << 9), _lb + (_i << 9));                        \
    }

__global__ __launch_bounds__(256) void attn_fused9_kernel(
    const short* __restrict__ qb4, const short* __restrict__ kfr0,
    const short* __restrict__ vfr0, const float* __restrict__ wagg,
    short* __restrict__ attb) {
    __shared__ __align__(16) short sbuf[2][8192];   // 2 x 16 KB (K 8K | V 8K)
    int tid = threadIdx.x;
    int w = tid >> 6, lane = tid & 63;
    int lq = lane & 15, quad = lane >> 4;
    int bh = blockIdx.x;                 // XCD-local: id%8 == bh%8
    int b = bh >> 4, h = bh & 15;
    int qrow0 = b * DL + (blockIdx.y << 6) + (w << 4);
    const float c_exp = 0.18033688f;    // log2(e)/8
    int fo = (quad << 7) + (lq << 3);   // fragment byte offset/2 within region

    float fin[4][4];
#pragma unroll
    for (int t = 0; t < 4; t++)
#pragma unroll
        for (int r = 0; r < 4; r++) fin[t][r] = 0.f;

#pragma unroll 1
    for (int s = 0; s < 4; s++) {
        int Ls = DL >> s;
        size_t doff = s == 0 ? 0 : s == 1 ? 4194304 : s == 2 ? 6291456 : 7340032;

        const short* qbase = qb4 + ((size_t)(qrow0 + lq) << 12) + (s << 10) +
                             (h << 6) + (quad << 3);
        short8 qf0 = __builtin_nontemporal_load((const short8*)qbase);
        short8 qf1 = __builtin_nontemporal_load((const short8*)(qbase + 32));

        const short* kt = kfr0 + doff + (((size_t)bh * (Ls >> 4)) << 10);
        const short* vt = vfr0 + doff + (((size_t)bh * (Ls >> 6)) << 12);

        float4v O[4];
        float lsum = 0.f;
#pragma unroll
        for (int t = 0; t < 4; t++) O[t] = (float4v){0.f, 0.f, 0.f, 0.f};

        int nt = Ls >> 6;                // 16 / 8 / 4 / 2
        STAGE9(0, 0);
#pragma unroll 1
        for (int c = 0; c < nt; c++) {
            __syncthreads();             // stage(cur) complete; prev reads done
            int cur = c & 1;
            if (c + 1 < nt) STAGE9(cur ^ 1, c + 1);
            const short* kl = sbuf[cur] + fo;
            const short* vl = sbuf[cur] + 4096 + fo;

            float4v S[4];
#pragma unroll
            for (int t = 0; t < 4; t++) {
                short8 kf0 = *(const short8*)(kl + (t << 10));
                short8 kf1 = *(const short8*)(kl + (t << 10) + 512);
                float4v zz = (float4v){0.f, 0.f, 0.f, 0.f};
                zz = __builtin_amdgcn_mfma_f32_16x16x32_bf16(kf0, qf0, zz, 0, 0, 0);
                S[t] = __builtin_amdgcn_mfma_f32_16x16x32_bf16(kf1, qf1, zz, 0, 0, 0);
            }

            unsigned wpk[8];
#pragma unroll
            for (int t = 0; t < 4; t++) {
                float p0 = fexp2(S[t][0] * c_exp);
                float p1 = fexp2(S[t][1] * c_exp);
                float p2 = fexp2(S[t][2] * c_exp);
                float p3 = fexp2(S[t][3] * c_exp);
                lsum += p0 + p1 + p2 + p3;
                wpk[2 * t]     = (__float_as_uint(p1) & 0xFFFF0000u) |
                                 (__float_as_uint(p0) >> 16);
                wpk[2 * t + 1] = (__float_as_uint(p3) & 0xFFFF0000u) |
                                 (__float_as_uint(p2) >> 16);
            }
            union AFU { unsigned u[4]; short8 s8; };
            AFU af0, af1;
            af0.u[0] = wpk[0]; af0.u[1] = wpk[1]; af0.u[2] = wpk[2]; af0.u[3] = wpk[3];
            af1.u[0] = wpk[4]; af1.u[1] = wpk[5]; af1.u[2] = wpk[6]; af1.u[3] = wpk[7];
#pragma unroll
            for (int t = 0; t < 4; t++) {
                short8 vf = *(const short8*)(vl + (t << 9));
                O[t] = __builtin_amdgcn_mfma_f32_16x16x32_bf16(af0.s8, vf, O[t], 0, 0, 0);
            }
#pragma unroll
            for (int t = 0; t < 4; t++) {
                short8 vf = *(const short8*)(vl + 2048 + (t << 9));
                O[t] = __builtin_amdgcn_mfma_f32_16x16x32_bf16(af1.s8, vf, O[t], 0, 0, 0);
            }
        }
        __syncthreads();                 // all reads done before next scale stages

        // denominator: lane-local partial over 16 k's; reduce across quads
        lsum += __shfl_xor(lsum, 16, 64);
        lsum += __shfl_xor(lsum, 32, 64);
        // redistribute l[q] to O's row layout (q = quad*4+r) and accumulate
        float wsc = wagg[s];
#pragma unroll
        for (int r = 0; r < 4; r++) {
            int sl = (lane & 48) | (((lane >> 4) << 2) + r);
            float lr = __shfl(lsum, sl, 64);
            float linv = wsc / lr;
#pragma unroll
            for (int t = 0; t < 4; t++) fin[t][r] += O[t][r] * linv;
        }
    }
#pragma unroll
    for (int r = 0; r < 4; r++) {
        size_t rbase = ((size_t)(qrow0 + (quad << 2) + r) << 10) + (h << 6) + lq;
#pragma unroll
        for (int t = 0; t < 4; t++)
            attb[rbase + (t << 4)] = f2bf(fin[t][r]);
    }
}

// ---------------------------------------------------------------- add-N + LN
// out = LN(a + sum_j pb[j*pstride + .]); OBF: also write bf16 copy.
// Partial-slab reads are nontemporal (read-once streams).
template <int NP, int OBF>
__global__ __launch_bounds__(256) void addlnN_kernel(
    const float* __restrict__ a, const float* __restrict__ pb, size_t pstride,
    const float* __restrict__ gam, const float* __restrict__ bet,
    float* __restrict__ out, short* __restrict__ outb) {
    __shared__ float redA[4], redB[4];
    int row = blockIdx.x, tid = threadIdx.x;
    size_t base = (size_t)row * DD + (tid << 2);
    float4v av = *(const float4v*)&a[base];
    float s0 = av[0], s1 = av[1], s2 = av[2], s3 = av[3];
#pragma unroll
    for (int j = 0; j < NP; j++) {
        float4v pv = __builtin_nontemporal_load(
            (const float4v*)&pb[(size_t)j * pstride + base]);
        s0 += pv[0]; s1 += pv[1]; s2 += pv[2]; s3 += pv[3];
    }
    float lsum = s0 + s1 + s2 + s3;
    float lsq = s0 * s0 + s1 * s1 + s2 * s2 + s3 * s3;
#pragma unroll
    for (int o = 32; o > 0; o >>= 1) {
        lsum += __shfl_down(lsum, o, 64);
        lsq += __shfl_down(lsq, o, 64);
    }
    int lane = tid & 63, wid = tid >> 6;
    if (lane == 0) { redA[wid] = lsum; redB[wid] = lsq; }
    __syncthreads();
    float tsum = redA[0] + redA[1] + redA[2] + redA[3];
    float tsq = redB[0] + redB[1] + redB[2] + redB[3];
    float mean = tsum * (1.0f / DD);
    float var = tsq * (1.0f / DD) - mean * mean;
    float rstd = rsqrtf(var + 1e-5f);
    float4v gv = *(const float4v*)&gam[tid << 2];
    float4v bev = *(const float4v*)&bet[tid << 2];
    float4v o;
    o[0] = (s0 - mean) * rstd * gv[0] + bev[0];
    o[1] = (s1 - mean) * rstd * gv[1] + bev[1];
    o[2] = (s2 - mean) * rstd * gv[2] + bev[2];
    o[3] = (s3 - mean) * rstd * gv[3] + bev[3];
    *(float4v*)&out[base] = o;
    if (OBF) {
        ushort4 u;
        u.x = (unsigned short)f2bf(o[0]);
        u.y = (unsigned short)f2bf(o[1]);
        u.z = (unsigned short)f2bf(o[2]);
        u.w = (unsigned short)f2bf(o[3]);
        *(ushort4*)&outb[base] = u;
    }
}

// ---------------------------------------------------------------- launcher
extern "C" void kernel_launch(void* const* d_in, const int* in_sizes, int n_in,
                              void* d_out, int out_size, void* d_ws, size_t ws_size,
                              hipStream_t stream) {
    (void)in_sizes; (void)n_in; (void)out_size; (void)ws_size;
    const float* x   = (const float*)d_in[0];
    const float* Wdc = (const float*)d_in[1];
    const float* bdc = (const float*)d_in[2];
    const float* Wdec= (const float*)d_in[3];
    const float* Wq  = (const float*)d_in[4];
    const float* Wk  = (const float*)d_in[5];
    const float* Wv  = (const float*)d_in[6];
    const float* Wo  = (const float*)d_in[7];
    const float* agg = (const float*)d_in[8];
    const float* g1  = (const float*)d_in[9];
    const float* be1 = (const float*)d_in[10];
    const float* g2  = (const float*)d_in[11];
    const float* be2 = (const float*)d_in[12];
    const float* W1  = (const float*)d_in[13];
    const float* b1  = (const float*)d_in[14];
    const float* W2  = (const float*)d_in[15];
    const float* b2  = (const float*)d_in[16];
    float* out = (float*)d_out;

    float* ws = (float*)d_ws;
    size_t off = 0;
    auto alloc = [&](size_t nfloats) { float* p = ws + off; off += nfloats; return p; };
    const size_t M1 = 1024 * 1024;
    short* wdc_bt  = (short*)alloc(3 * M1 / 2);
    short* wdec_bt = (short*)alloc(3 * M1);
    short* wq4t    = (short*)alloc(2 * M1);
    short* wkvt    = (short*)alloc(4 * M1);
    short* wot     = (short*)alloc(M1 / 2);
    short* w1t     = (short*)alloc(2 * M1);
    short* w2t     = (short*)alloc(2 * M1);
    float* wagg    = alloc(64);
    short* xpad    = (short*)alloc(2105344);
    // activation buffers: contiguous rows 0..7679 for grouped KV GEMM
    short* xcb     = (short*)alloc(2 * M1);         // rows [0,4096)
    short* s1b     = (short*)alloc(M1);             // rows [4096,6144)
    short* s2b     = (short*)alloc(M1 / 2);         // rows [6144,7168)
    short* s3b     = (short*)alloc(M1 / 4);         // rows [7168,7680)
    short* qb4     = (short*)alloc(8 * M1);         // later FFN hidden; conv partials first
    short* kvall   = (short*)alloc(7 * M1 + M1 / 2);// V-half rows; FFN2 partials later
    short* kfrall  = (short*)alloc(3 * M1 + 3 * M1 / 4);
    short* vfrall  = (short*)alloc(3 * M1 + 3 * M1 / 4);
    short* attb    = (short*)alloc(2 * M1);
    float* x1      = alloc(4 * M1);
    short* x1b     = (short*)alloc(2 * M1);
    float* pkbuf   = alloc(8 * M1);                 // Wo/dec split-K partials
    short* hb      = qb4;                           // FFN hidden [4096][4096] bf16
    float* convp   = (float*)qb4;                   // conv tap partials (12M fp32:
                                                    //  qb4 8M + kvall first 4M, contiguous)
    float* pk4     = (float*)kvall;                 // FFN2 4x4M fp32 partials
                                                    //  (kvall+kfrall+vfrall+1M of attb; all
                                                    //  dead after attention / Wo)

    dim3 blk(256);
    // ---- fused prep
    prep_all_kernel<<<dim3(74817), blk, 0, stream>>>(
        Wdc, Wdec, Wq, Wk, Wv, Wo, W1, W2, x, agg,
        wdc_bt, wdec_bt, wq4t, wkvt, wot, w1t, w2t, xpad, wagg,
        out + (size_t)DB * DL * DD);

    // 1. dilated conv: tap-split x3 + relu/bias combine
    convdil_pk_kernel<<<dim3(DD / 128, DB * DL / 128, 3), blk, 0, stream>>>(
        xpad, wdc_bt, convp);
    convcomb_kernel<<<dim3(4 * M1 / (256 * 4)), blk, 0, stream>>>(convp, bdc, xcb);

    // 2. decomposition convs: split-K x4 each (512/256/128 blocks) + sum-cast
    mgemm_pk_kernel<<<dim3(8, 16, 4), blk, 0, stream>>>(
        xcb, wdec_bt, nullptr, pkbuf, 2048, DD, 2 * DD, 512);
    sumcast4_kernel<<<dim3(2 * M1 / 1024), blk, 0, stream>>>(pkbuf, 2 * M1, s1b);
    mgemm_pk_kernel<<<dim3(8, 8, 4), blk, 0, stream>>>(
        s1b, wdec_bt + 2 * M1, nullptr, pkbuf, 1024, DD, 2 * DD, 512);
    sumcast4_kernel<<<dim3(M1 / 1024), blk, 0, stream>>>(pkbuf, M1, s2b);
    mgemm_pk_kernel<<<dim3(8, 4, 4), blk, 0, stream>>>(
        s2b, wdec_bt + 4 * M1, nullptr, pkbuf, 512, DD, 2 * DD, 512);
    sumcast4_kernel<<<dim3(M1 / 2048), blk, 0, stream>>>(pkbuf, M1 / 2, s3b);

    // 3a. batched Q projection (all 4 scales, N=4096)
    mgemm_kernel<0, 1><<<dim3(32, 32), blk, 0, stream>>>(
        xcb, wq4t, nullptr, qb4, DB * DL, 4 * DD, DD);

    // 3b. grouped K|V projection (K-half straight to fragment layout)
    kvgemm_kernel<<<dim3(16, 60), blk, 0, stream>>>(xcb, wkvt, kvall, kfrall);

    // 3c. V fragment prep (k-permuted, slot-group-major for LDS staging)
    vfrag_all_kernel<<<dim3(7680), blk, 0, stream>>>(kvall, vfrall);

    // 3d. fused attention, block-shared K/V via LDS double-buffer,
    //     in-register P, XCD-locality swizzled
    attn_fused9_kernel<<<dim3(DB * DH, DL / 64), blk, 0, stream>>>(
        qb4, kfrall, vfrall, wagg, attb);

    // 4. shared output projection (split-K x2)
    mgemm_pk_kernel<<<dim3(8, 32, 2), blk, 0, stream>>>(
        attb, wot, nullptr, pkbuf, DB * DL, DD, DD, DD / 2);

    // 5. residual + LN1 (2 partials)
    addlnN_kernel<2, 1><<<dim3(DB * DL), blk, 0, stream>>>(
        x, pkbuf, 4 * M1, g1, be1, x1, x1b);

    // 6. FFN: GELU GEMM then split-K x4 down-projection (1024 blocks)
    mgemm_kernel<1, 1><<<dim3(DF / 128, (DB * DL) / 128), blk, 0, stream>>>(
        x1b, w1t, b1, hb, DB * DL, DF, DD);
    mgemm_pk_kernel<<<dim3(8, 32, 4), blk, 0, stream>>>(
        hb, w2t, b2, pk4, DB * DL, DD, DF, DF / 4);

    // 7. residual + LN2 -> out (4 partials)
    addlnN_kernel<4, 0><<<dim3(DB * DL), blk, 0, stream>>>(
        x1, pk4, 4 * M1, g2, be2, out, nullptr);
}

// Round 12
// 628.897 us; speedup vs baseline: 1.1200x; 1.0613x over previous
//
#include <hip/hip_runtime.h>
#include <cstddef>

#define DB 4
#define DL 1024
#define DD 1024
#define DH 16
#define DF 4096

typedef __attribute__((ext_vector_type(8))) short short8;
typedef __attribute__((ext_vector_type(4))) float float4v;

static __device__ __forceinline__ short f2bf(float f) {
    unsigned u = __float_as_uint(f);
    unsigned r = (u + 0x7FFFu + ((u >> 16) & 1u)) >> 16;   // RNE
    return (short)r;
}

#define GLOAD_LDS16(gp, lp)                                                          \
    __builtin_amdgcn_global_load_lds(                                                \
        (const __attribute__((address_space(1))) void*)(gp),                         \
        (__attribute__((address_space(3))) void*)(lp), 16, 0, 0)

// ---------------------------------------------------------------- mega-prep
__global__ __launch_bounds__(256) void prep_all_kernel(
    const float* __restrict__ Wdc, const float* __restrict__ Wdec,
    const float* __restrict__ Wq, const float* __restrict__ Wk,
    const float* __restrict__ Wv, const float* __restrict__ Wo,
    const float* __restrict__ W1, const float* __restrict__ W2,
    const float* __restrict__ x, const float* __restrict__ agg,
    short* __restrict__ wdc_bt, short* __restrict__ wdec_bt,
    short* __restrict__ wq4t, short* __restrict__ wkvt, short* __restrict__ wot,
    short* __restrict__ w1t, short* __restrict__ w2t, short* __restrict__ xpad,
    float* __restrict__ wagg, float* __restrict__ aux) {
    __shared__ float tile[32][33];
    const size_t M1 = 1024 * 1024;
    int blk = blockIdx.x, tid = threadIdx.x;
    if (blk < 12288) {
        int idx = blk * 256 + tid;
        int i = idx & 1023, o = (idx >> 10) & 1023, k = idx >> 20;
        wdc_bt[idx] = f2bf(Wdc[((size_t)o * 1024 + i) * 3 + k]);
        return;
    }
    if (blk < 36864) {
        int idx = (blk - 12288) * 256 + tid;
        int i = idx & 1023, k2 = (idx >> 10) & 1, n = (idx >> 11) & 1023, s = idx >> 21;
        wdec_bt[idx] = f2bf(Wdec[(((size_t)(s * 1024 + n)) * 1024 + i) * 2 + k2]);
        return;
    }
    if (blk < 58368) {
        const float* src; short* dst; int K, N, bx, by;
        if (blk < 50176) {
            int r = blk - 36864;
            int z = r >> 10, rem = r & 1023;
            bx = rem & 31; by = rem >> 5; K = 1024; N = 1024;
            if (z < 4)      { src = Wq + (size_t)z * M1;       dst = wq4t + (size_t)z * M1; }
            else if (z < 8) { src = Wk + (size_t)(z - 4) * M1; dst = wkvt + (size_t)(z - 4) * 2 * M1; }
            else if (z < 12){ src = Wv;                        dst = wkvt + (size_t)(z - 8) * 2 * M1 + M1; }
            else            { src = Wo;                        dst = wot; }
        } else if (blk < 54272) {
            int r = blk - 50176;
            bx = r & 127; by = r >> 7; K = 1024; N = 4096; src = W1; dst = w1t;
        } else {
            int r = blk - 54272;
            bx = r & 31; by = r >> 5; K = 4096; N = 1024; src = W2; dst = w2t;
        }
        int n0 = bx << 5, k0 = by << 5;
        int cc = tid & 31, rr = tid >> 5;
#pragma unroll
        for (int p = 0; p < 4; p++) {
            int kk = (p << 3) + rr;
            tile[kk][cc] = src[(size_t)(k0 + kk) * N + n0 + cc];
        }
        __syncthreads();
#pragma unroll
        for (int p = 0; p < 4; p++) {
            int nn = (p << 3) + rr;
            dst[(size_t)(n0 + nn) * K + k0 + cc] = f2bf(tile[cc][nn]);
        }
        return;
    }
    if (blk < 74816) {
        int idx = (blk - 58368) * 256 + tid;
        int d = idx & 1023;
        int row = (idx >> 10) % 1028;
        int b = (idx >> 10) / 1028;
        int l = row - 2;
        float v = (l >= 0 && l < DL) ? x[((size_t)(b * DL + l)) * DD + d] : 0.f;
        xpad[idx] = f2bf(v);
        return;
    }
    if (tid == 0) {
        float l0 = agg[0], l1 = agg[1], l2 = agg[2], l3 = agg[3];
        float m = fmaxf(fmaxf(l0, l1), fmaxf(l2, l3));
        float e0 = __expf(l0 - m), e1 = __expf(l1 - m);
        float e2 = __expf(l2 - m), e3 = __expf(l3 - m);
        float ssum = e0 + e1 + e2 + e3;
        float w0 = e0 / ssum, w1 = e1 / ssum, w2 = e2 / ssum, w3 = e3 / ssum;
        wagg[0] = w0; wagg[1] = w1; wagg[2] = w2; wagg[3] = w3;
        *aux = -(w0 * logf(w0 + 1e-9f) + w1 * logf(w1 + 1e-9f) +
                 w2 * logf(w2 + 1e-9f) + w3 * logf(w3 + 1e-9f));
    }
}

// ---------------------------------------------------------------- MFMA GEMM
// Measured-best dbuf schedule + RESIDENCY FIX: grid is exactly 4 blocks/CU but
// 144 unified regs/wave (80 VGPR + 64 AGPR acc) allowed only 3 waves/SIMD ->
// 3+1 straggler rounds (measured Occupancy 22%, half the wall at 1 block/CU).
// Inner loop restructured to hold only bfr[4]+one af (live frags 64->40) and
// __launch_bounds__(256,4) caps at 128 regs -> 4 blocks/CU, single round.
template <int ACT, int OBF>
__global__ __launch_bounds__(256, 4) void mgemm_kernel(
    const short* __restrict__ A, const short* __restrict__ Bt,
    const float* __restrict__ bias, void* __restrict__ Cv,
    int M, int N, int K) {
    __shared__ short As[2][128 * 32];
    __shared__ short Bs[2][128 * 32];
    int tid = threadIdx.x;
    int wave = tid >> 6, lane = tid & 63;
    int lq = lane & 15, quad = lane >> 4;
    int m0 = blockIdx.y << 7, n0 = blockIdx.x << 7;
    int wm = (wave & 1) << 6, wn = (wave >> 1) << 6;
    int r0 = tid >> 2, r1 = (256 + tid) >> 2;
    int kc0 = (tid & 3) << 3;
    const short* Ag0 = A + (size_t)(m0 + r0) * K + kc0;
    const short* Ag1 = A + (size_t)(m0 + r1) * K + kc0;
    const short* Bg0 = Bt + (size_t)(n0 + r0) * K + kc0;
    const short* Bg1 = Bt + (size_t)(n0 + r1) * K + kc0;
    float4v acc[4][4];
#pragma unroll
    for (int mi = 0; mi < 4; mi++)
#pragma unroll
        for (int ni = 0; ni < 4; ni++) acc[mi][ni] = (float4v){0.f, 0.f, 0.f, 0.f};

#define MG_STAGE(BUF, KO)                                                \
    {                                                                    \
        GLOAD_LDS16(Ag0 + (KO), As[BUF] + tid * 8);                      \
        GLOAD_LDS16(Ag1 + (KO), As[BUF] + (256 + tid) * 8);              \
        GLOAD_LDS16(Bg0 + (KO), Bs[BUF] + tid * 8);                      \
        GLOAD_LDS16(Bg1 + (KO), Bs[BUF] + (256 + tid) * 8);              \
    }
    int nk = K >> 5;
    MG_STAGE(0, 0);
    __syncthreads();
    for (int t = 0; t < nk; t++) {
        int cur = t & 1;
        if (t + 1 < nk) MG_STAGE(cur ^ 1, (t + 1) << 5);
        short8 bfr[4];
#pragma unroll
        for (int ni = 0; ni < 4; ni++)
            bfr[ni] = *(const short8*)(Bs[cur] + ((wn + (ni << 4) + lq) << 5) + (quad << 3));
#pragma unroll
        for (int mi = 0; mi < 4; mi++) {
            short8 af = *(const short8*)(As[cur] + ((wm + (mi << 4) + lq) << 5) + (quad << 3));
#pragma unroll
            for (int ni = 0; ni < 4; ni++)
                acc[mi][ni] = __builtin_amdgcn_mfma_f32_16x16x32_bf16(
                    af, bfr[ni], acc[mi][ni], 0, 0, 0);
        }
        __syncthreads();
    }
#undef MG_STAGE
#pragma unroll
    for (int ni = 0; ni < 4; ni++) {
        int col = n0 + wn + (ni << 4) + lq;
        float bv = bias ? bias[col] : 0.f;
#pragma unroll
        for (int mi = 0; mi < 4; mi++) {
#pragma unroll
            for (int r = 0; r < 4; r++) {
                int row = m0 + wm + (mi << 4) + (quad << 2) + r;
                float v = acc[mi][ni][r] + bv;
                if (ACT == 1) v = 0.5f * v * (1.0f + erff(v * 0.70710678118654752f));
                if (OBF) ((short*)Cv)[(size_t)row * N + col] = f2bf(v);
                else ((float*)Cv)[(size_t)row * N + col] = v;
            }
        }
    }
}

// ---------------------------------------------------------------- grouped KV GEMM
// K-half columns written directly in K-fragment layout; V-half row-major.
// Same dbuf schedule + residency fix.
__global__ __launch_bounds__(256, 4) void kvgemm_kernel(
    const short* __restrict__ acts, const short* __restrict__ wkvt,
    short* __restrict__ kvall, short* __restrict__ kfrall) {
    __shared__ short As[2][128 * 32];
    __shared__ short Bs[2][128 * 32];
    int my = blockIdx.y;                       // 0..59
    int s = my < 32 ? 0 : my < 48 ? 1 : my < 56 ? 2 : 3;
    int m0 = my << 7;
    int rb = s == 0 ? 0 : s == 1 ? 4096 : s == 2 ? 6144 : 7168;
    size_t doff = s == 0 ? 0 : s == 1 ? 4194304 : s == 2 ? 6291456 : 7340032;
    int Ls = DL >> s;
    const short* Bt = wkvt + (size_t)s * 2097152;
    const int K = 1024, N = 2048;
    int tid = threadIdx.x;
    int wave = tid >> 6, lane = tid & 63;
    int lq = lane & 15, quad = lane >> 4;
    int n0 = blockIdx.x << 7;
    int wm = (wave & 1) << 6, wn = (wave >> 1) << 6;
    int r0 = tid >> 2, r1 = (256 + tid) >> 2;
    int kc0 = (tid & 3) << 3;
    const short* Ag0 = acts + (size_t)(m0 + r0) * K + kc0;
    const short* Ag1 = acts + (size_t)(m0 + r1) * K + kc0;
    const short* Bg0 = Bt + (size_t)(n0 + r0) * K + kc0;
    const short* Bg1 = Bt + (size_t)(n0 + r1) * K + kc0;
    float4v acc[4][4];
#pragma unroll
    for (int mi = 0; mi < 4; mi++)
#pragma unroll
        for (int ni = 0; ni < 4; ni++) acc[mi][ni] = (float4v){0.f, 0.f, 0.f, 0.f};

#define KV_STAGE(BUF, KO)                                                \
    {                                                                    \
        GLOAD_LDS16(Ag0 + (KO), As[BUF] + tid * 8);                      \
        GLOAD_LDS16(Ag1 + (KO), As[BUF] + (256 + tid) * 8);              \
        GLOAD_LDS16(Bg0 + (KO), Bs[BUF] + tid * 8);                      \
        GLOAD_LDS16(Bg1 + (KO), Bs[BUF] + (256 + tid) * 8);              \
    }
    int nk = K >> 5;
    KV_STAGE(0, 0);
    __syncthreads();
    for (int t = 0; t < nk; t++) {
        int cur = t & 1;
        if (t + 1 < nk) KV_STAGE(cur ^ 1, (t + 1) << 5);
        short8 bfr[4];
#pragma unroll
        for (int ni = 0; ni < 4; ni++)
            bfr[ni] = *(const short8*)(Bs[cur] + ((wn + (ni << 4) + lq) << 5) + (quad << 3));
#pragma unroll
        for (int mi = 0; mi < 4; mi++) {
            short8 af = *(const short8*)(As[cur] + ((wm + (mi << 4) + lq) << 5) + (quad << 3));
#pragma unroll
            for (int ni = 0; ni < 4; ni++)
                acc[mi][ni] = __builtin_amdgcn_mfma_f32_16x16x32_bf16(
                    af, bfr[ni], acc[mi][ni], 0, 0, 0);
        }
        __syncthreads();
    }
#undef KV_STAGE
    bool isK = (n0 < 1024);
#pragma unroll
    for (int ni = 0; ni < 4; ni++) {
        int col = n0 + wn + (ni << 4) + lq;
        if (isK) {
            int h = col >> 6, dc = (col >> 3) & 7, di = col & 7;
#pragma unroll
            for (int mi = 0; mi < 4; mi++)
#pragma unroll
                for (int r = 0; r < 4; r++) {
                    int row = m0 + wm + (mi << 4) + (quad << 2) + r;
                    int jg = row - rb;
                    int b = jg >> (10 - s);
                    int j = jg & (Ls - 1);
                    int bh = (b << 4) | h;
                    size_t addr = doff + (((size_t)bh * (Ls >> 4) + (j >> 4)) << 10) +
                                  (dc << 7) + ((j & 15) << 3) + di;
                    kfrall[addr] = f2bf(acc[mi][ni][r]);
                }
        } else {
#pragma unroll
            for (int mi = 0; mi < 4; mi++)
#pragma unroll
                for (int r = 0; r < 4; r++) {
                    int row = m0 + wm + (mi << 4) + (quad << 2) + r;
                    kvall[(size_t)row * N + col] = f2bf(acc[mi][ni][r]);
                }
        }
    }
}

// ---------------------------------------------------------------- split-K GEMM
// blockIdx.z selects K-slice; fp32 partials to Cout + z*M*N (nontemporal —
// full-line fp32 streams; measured win). Dbuf schedule + residency fix.
__global__ __launch_bounds__(256, 4) void mgemm_pk_kernel(
    const short* __restrict__ A, const short* __restrict__ Bt,
    const float* __restrict__ bias, float* __restrict__ Cout,
    int M, int N, int Kfull, int KH) {
    __shared__ short As[2][128 * 32];
    __shared__ short Bs[2][128 * 32];
    int kz = blockIdx.z;
    const short* Ab = A + (size_t)kz * KH;
    const short* Btb = Bt + (size_t)kz * KH;
    float* Co = Cout + (size_t)kz * M * N;
    int tid = threadIdx.x;
    int wave = tid >> 6, lane = tid & 63;
    int lq = lane & 15, quad = lane >> 4;
    int m0 = blockIdx.y << 7, n0 = blockIdx.x << 7;
    int wm = (wave & 1) << 6, wn = (wave >> 1) << 6;
    int r0 = tid >> 2, r1 = (256 + tid) >> 2;
    int kc0 = (tid & 3) << 3;
    const short* Ag0 = Ab + (size_t)(m0 + r0) * Kfull + kc0;
    const short* Ag1 = Ab + (size_t)(m0 + r1) * Kfull + kc0;
    const short* Bg0 = Btb + (size_t)(n0 + r0) * Kfull + kc0;
    const short* Bg1 = Btb + (size_t)(n0 + r1) * Kfull + kc0;
    float4v acc[4][4];
#pragma unroll
    for (int mi = 0; mi < 4; mi++)
#pragma unroll
        for (int ni = 0; ni < 4; ni++) acc[mi][ni] = (float4v){0.f, 0.f, 0.f, 0.f};

#define PK_STAGE(BUF, KO)                                                \
    {                                                                    \
        GLOAD_LDS16(Ag0 + (KO), As[BUF] + tid * 8);                      \
        GLOAD_LDS16(Ag1 + (KO), As[BUF] + (256 + tid) * 8);              \
        GLOAD_LDS16(Bg0 + (KO), Bs[BUF] + tid * 8);                      \
        GLOAD_LDS16(Bg1 + (KO), Bs[BUF] + (256 + tid) * 8);              \
    }
    int nk = KH >> 5;
    PK_STAGE(0, 0);
    __syncthreads();
    for (int t = 0; t < nk; t++) {
        int cur = t & 1;
        if (t + 1 < nk) PK_STAGE(cur ^ 1, (t + 1) << 5);
        short8 bfr[4];
#pragma unroll
        for (int ni = 0; ni < 4; ni++)
            bfr[ni] = *(const short8*)(Bs[cur] + ((wn + (ni << 4) + lq) << 5) + (quad << 3));
#pragma unroll
        for (int mi = 0; mi < 4; mi++) {
            short8 af = *(const short8*)(As[cur] + ((wm + (mi << 4) + lq) << 5) + (quad << 3));
#pragma unroll
            for (int ni = 0; ni < 4; ni++)
                acc[mi][ni] = __builtin_amdgcn_mfma_f32_16x16x32_bf16(
                    af, bfr[ni], acc[mi][ni], 0, 0, 0);
        }
        __syncthreads();
    }
#undef PK_STAGE
#pragma unroll
    for (int ni = 0; ni < 4; ni++) {
        int col = n0 + wn + (ni << 4) + lq;
        float bv = (bias && kz == 0) ? bias[col] : 0.f;
#pragma unroll
        for (int mi = 0; mi < 4; mi++)
#pragma unroll
            for (int r = 0; r < 4; r++) {
                int row = m0 + wm + (mi << 4) + (quad << 2) + r;
                __builtin_nontemporal_store(acc[mi][ni][r] + bv,
                                            &Co[(size_t)row * N + col]);
            }
    }
}

// sum of 4 fp32 partial slabs -> bf16 (nt loads: read-once streams)
__global__ __launch_bounds__(256) void sumcast4_kernel(
    const float* __restrict__ p, size_t stride, short* __restrict__ outp) {
    int idx = (blockIdx.x * 256 + threadIdx.x) << 2;
    float4v a0 = __builtin_nontemporal_load((const float4v*)&p[idx]);
    float4v a1 = __builtin_nontemporal_load((const float4v*)&p[stride + idx]);
    float4v a2 = __builtin_nontemporal_load((const float4v*)&p[2 * stride + idx]);
    float4v a3 = __builtin_nontemporal_load((const float4v*)&p[3 * stride + idx]);
    ushort4 u;
    u.x = (unsigned short)f2bf(a0[0] + a1[0] + a2[0] + a3[0]);
    u.y = (unsigned short)f2bf(a0[1] + a1[1] + a2[1] + a3[1]);
    u.z = (unsigned short)f2bf(a0[2] + a1[2] + a2[2] + a3[2]);
    u.w = (unsigned short)f2bf(a0[3] + a1[3] + a2[3] + a3[3]);
    *(ushort4*)&outp[idx] = u;
}

// ---------------------------------------------------------------- conv tap-split
// Dbuf schedule + residency fix; nt fp32 partial stores.
__global__ __launch_bounds__(256, 4) void convdil_pk_kernel(
    const short* __restrict__ xp, const short* __restrict__ Wt,
    float* __restrict__ pbuf) {
    __shared__ short As[2][128 * 32];
    __shared__ short Bs[2][128 * 32];
    int kp = blockIdx.z;
    int tid = threadIdx.x;
    int wave = tid >> 6, lane = tid & 63;
    int lq = lane & 15, quad = lane >> 4;
    int m0 = blockIdx.y << 7, n0 = blockIdx.x << 7;
    int wm = (wave & 1) << 6, wn = (wave >> 1) << 6;
    int b = m0 >> 10, ll0 = m0 & 1023;
    int r0 = tid >> 2, r1 = (256 + tid) >> 2;
    int kc = (tid & 3) << 3;
    float* Co = pbuf + (size_t)kp * DB * DL * DD;
    const short* Abase = xp + ((size_t)(b * 1028 + ll0 + 2 * kp)) * DD + kc;
    const short* Bbase = Wt + (size_t)kp * DD * DD;
    const short* Bg0 = Bbase + (size_t)(n0 + r0) * DD + kc;
    const short* Bg1 = Bbase + (size_t)(n0 + r1) * DD + kc;
    float4v acc[4][4];
#pragma unroll
    for (int mi = 0; mi < 4; mi++)
#pragma unroll
        for (int ni = 0; ni < 4; ni++) acc[mi][ni] = (float4v){0.f, 0.f, 0.f, 0.f};

#define CD_STAGE(BUF, KO)                                                        \
    {                                                                            \
        GLOAD_LDS16(Abase + (size_t)r0 * DD + (KO), As[BUF] + tid * 8);          \
        GLOAD_LDS16(Abase + (size_t)r1 * DD + (KO), As[BUF] + (256 + tid) * 8);  \
        GLOAD_LDS16(Bg0 + (KO), Bs[BUF] + tid * 8);                              \
        GLOAD_LDS16(Bg1 + (KO), Bs[BUF] + (256 + tid) * 8);                      \
    }
    int nk = DD >> 5;
    CD_STAGE(0, 0);
    __syncthreads();
    for (int t = 0; t < nk; t++) {
        int cur = t & 1;
        if (t + 1 < nk) CD_STAGE(cur ^ 1, (t + 1) << 5);
        short8 bfr[4];
#pragma unroll
        for (int ni = 0; ni < 4; ni++)
            bfr[ni] = *(const short8*)(Bs[cur] + ((wn + (ni << 4) + lq) << 5) + (quad << 3));
#pragma unroll
        for (int mi = 0; mi < 4; mi++) {
            short8 af = *(const short8*)(As[cur] + ((wm + (mi << 4) + lq) << 5) + (quad << 3));
#pragma unroll
            for (int ni = 0; ni < 4; ni++)
                acc[mi][ni] = __builtin_amdgcn_mfma_f32_16x16x32_bf16(
                    af, bfr[ni], acc[mi][ni], 0, 0, 0);
        }
        __syncthreads();
    }
#undef CD_STAGE
#pragma unroll
    for (int ni = 0; ni < 4; ni++) {
        int col = n0 + wn + (ni << 4) + lq;
#pragma unroll
        for (int mi = 0; mi < 4; mi++)
#pragma unroll
            for (int r = 0; r < 4; r++) {
                int row = m0 + wm + (mi << 4) + (quad << 2) + r;
                __builtin_nontemporal_store(acc[mi][ni][r],
                                            &Co[(size_t)row * DD + col]);
            }
    }
}

// xcb = bf16(relu(p0+p1+p2 + bias)), 4 elems/thread over 4M
__global__ __launch_bounds__(256) void convcomb_kernel(
    const float* __restrict__ pbuf, const float* __restrict__ bvec,
    short* __restrict__ xcb) {
    const size_t M4 = (size_t)DB * DL * DD;
    int idx = (blockIdx.x * 256 + threadIdx.x) << 2;
    int col = idx & 1023;
    float4v p0 = __builtin_nontemporal_load((const float4v*)&pbuf[idx]);
    float4v p1 = __builtin_nontemporal_load((const float4v*)&pbuf[M4 + idx]);
    float4v p2 = __builtin_nontemporal_load((const float4v*)&pbuf[2 * M4 + idx]);
    float4v bb = *(const float4v*)&bvec[col];
    ushort4 u;
    u.x = (unsigned short)f2bf(fmaxf(p0[0] + p1[0] + p2[0] + bb[0], 0.f));
    u.y = (unsigned short)f2bf(fmaxf(p0[1] + p1[1] + p2[1] + bb[1], 0.f));
    u.z = (unsigned short)f2bf(fmaxf(p0[2] + p1[2] + p2[2] + bb[2], 0.f));
    u.w = (unsigned short)f2bf(fmaxf(p0[3] + p1[3] + p2[3] + bb[3], 0.f));
    *(ushort4*)&xcb[idx] = u;
}

// ---------------------------------------------------------------- V fragment prep
// k-axis within each 32-chunk PERMUTED to match the in-register P layout of the
// swapped-QK^T attention: slot m holds k-offset perm(m)=16*((m>>2)&1)+4*(m>>3)+(m&3).
// Within each (ks,t) 512-short block the element position is SLOT-GROUP-MAJOR:
// pos(slot,d) = (slot>>3)*128 + d*8 + (slot&7), so an attn lane (lq,quad) reads
// its 8 slots at byte offset quad*256+lq*16 — contiguous-1KB-per-wave,
// bank-conflict-free (global_load_lds staging can't pad).
__global__ __launch_bounds__(256) void vfrag_all_kernel(const short* __restrict__ kvall,
                                                        short* __restrict__ vfr0) {
    __shared__ short tile[32][33];
    int flat = blockIdx.x;                          // 0..7679
    int s, base, rb;
    size_t doff;
    if (flat < 4096)      { s = 0; base = 0;    rb = 0;    doff = 0; }
    else if (flat < 6144) { s = 1; base = 4096; rb = 4096; doff = 4194304; }
    else if (flat < 7168) { s = 2; base = 6144; rb = 6144; doff = 6291456; }
    else                  { s = 3; base = 7168; rb = 7168; doff = 7340032; }
    int rem = flat - base;
    int Ls = DL >> s;
    int nt = Ls >> 5;
    int j0t = rem & (nt - 1);
    int rest = rem >> (5 - s);
    int dt = rest & 1;
    int bh = rest >> 1;
    int j0 = j0t << 5, d0 = dt << 5;
    int b = bh >> 4, h = bh & 15;
    int tid = threadIdx.x;
    int cc = tid & 31, rr = tid >> 5;
#pragma unroll
    for (int p = 0; p < 4; p++) {
        int jj = (p << 3) + rr;
        tile[jj][cc] = kvall[((size_t)(rb + b * Ls + j0 + jj) << 11) + 1024 +
                             (h << 6) + d0 + cc];
    }
    __syncthreads();
    int c = j0 >> 6, ks = (j0 >> 5) & 1;
    int pc = (((cc >> 2) & 1) << 4) | ((cc >> 3) << 2) | (cc & 3);   // perm(cc)
#pragma unroll
    for (int p = 0; p < 4; p++) {
        int d = d0 + (p << 3) + rr;
        int tt = d >> 4, lqv = d & 15;
        size_t off = doff + (((size_t)bh * (Ls >> 6) + c) << 12) + (ks << 11) +
                     (tt << 9) + ((cc & 24) << 4) + (lqv << 3) + (cc & 7);
        vfr0[off] = tile[pc][(p << 3) + rr];
    }
}

// ---------------------------------------------------------------- attention
// In-register-P flash attention (swapped QK^T) with block-shared K/V staged
// through LDS (global_load_lds, double-buffered, one barrier per tile).
static __device__ __forceinline__ float fexp2(float x) {
    return __builtin_amdgcn_exp2f(x);
}

#define STAGE9(BUF, TILE)                                                         \
    {                                                                             \
        const short* _gs = (w < 2)                                                \
            ? kt + ((size_t)(TILE) << 12) + (w << 11) + (lane << 3)               \
            : vt + ((size_t)(TILE) << 12) + ((w - 2) << 11) + (lane << 3);        \
        short* _lb = sbuf[BUF] + (w << 11) + (lane << 3);                         \
        _Pragma("unroll") for (int _i = 0; _i < 4; _i++)                          \
            GLOAD_LDS16(_gs + (_i << 9), _lb + (_i << 9));                        \
    }

__global__ __launch_bounds__(256) void attn_fused9_kernel(
    const short* __restrict__ qb4, const short* __restrict__ kfr0,
    const short* __restrict__ vfr0, const float* __restrict__ wagg,
    short* __restrict__ attb) {
    __shared__ __align__(16) short sbuf[2][8192];   // 2 x 16 KB (K 8K | V 8K)
    int tid = threadIdx.x;
    int w = tid >> 6, lane = tid & 63;
    int lq = lane & 15, quad = lane >> 4;
    int bh = blockIdx.x;                 // XCD-local: id%8 == bh%8
    int b = bh >> 4, h = bh & 15;
    int qrow0 = b * DL + (blockIdx.y << 6) + (w << 4);
    const float c_exp = 0.18033688f;    // log2(e)/8
    int fo = (quad << 7) + (lq << 3);   // fragment byte offset/2 within region

    float fin[4][4];
#pragma unroll
    for (int t = 0; t < 4; t++)
#pragma unroll
        for (int r = 0; r < 4; r++) fin[t][r] = 0.f;

#pragma unroll 1
    for (int s = 0; s < 4; s++) {
        int Ls = DL >> s;
        size_t doff = s == 0 ? 0 : s == 1 ? 4194304 : s == 2 ? 6291456 : 7340032;

        const short* qbase = qb4 + ((size_t)(qrow0 + lq) << 12) + (s << 10) +
                             (h << 6) + (quad << 3);
        short8 qf0 = __builtin_nontemporal_load((const short8*)qbase);
        short8 qf1 = __builtin_nontemporal_load((const short8*)(qbase + 32));

        const short* kt = kfr0 + doff + (((size_t)bh * (Ls >> 4)) << 10);
        const short* vt = vfr0 + doff + (((size_t)bh * (Ls >> 6)) << 12);

        float4v O[4];
        float lsum = 0.f;
#pragma unroll
        for (int t = 0; t < 4; t++) O[t] = (float4v){0.f, 0.f, 0.f, 0.f};

        int nt = Ls >> 6;                // 16 / 8 / 4 / 2
        STAGE9(0, 0);
#pragma unroll 1
        for (int c = 0; c < nt; c++) {
            __syncthreads();             // stage(cur) complete; prev reads done
            int cur = c & 1;
            if (c + 1 < nt) STAGE9(cur ^ 1, c + 1);
            const short* kl = sbuf[cur] + fo;
            const short* vl = sbuf[cur] + 4096 + fo;

            float4v S[4];
#pragma unroll
            for (int t = 0; t < 4; t++) {
                short8 kf0 = *(const short8*)(kl + (t << 10));
                short8 kf1 = *(const short8*)(kl + (t << 10) + 512);
                float4v zz = (float4v){0.f, 0.f, 0.f, 0.f};
                zz = __builtin_amdgcn_mfma_f32_16x16x32_bf16(kf0, qf0, zz, 0, 0, 0);
                S[t] = __builtin_amdgcn_mfma_f32_16x16x32_bf16(kf1, qf1, zz, 0, 0, 0);
            }

            unsigned wpk[8];
#pragma unroll
            for (int t = 0; t < 4; t++) {
                float p0 = fexp2(S[t][0] * c_exp);
                float p1 = fexp2(S[t][1] * c_exp);
                float p2 = fexp2(S[t][2] * c_exp);
                float p3 = fexp2(S[t][3] * c_exp);
                lsum += p0 + p1 + p2 + p3;
                wpk[2 * t]     = (__float_as_uint(p1) & 0xFFFF0000u) |
                                 (__float_as_uint(p0) >> 16);
                wpk[2 * t + 1] = (__float_as_uint(p3) & 0xFFFF0000u) |
                                 (__float_as_uint(p2) >> 16);
            }
            union AFU { unsigned u[4]; short8 s8; };
            AFU af0, af1;
            af0.u[0] = wpk[0]; af0.u[1] = wpk[1]; af0.u[2] = wpk[2]; af0.u[3] = wpk[3];
            af1.u[0] = wpk[4]; af1.u[1] = wpk[5]; af1.u[2] = wpk[6]; af1.u[3] = wpk[7];
#pragma unroll
            for (int t = 0; t < 4; t++) {
                short8 vf = *(const short8*)(vl + (t << 9));
                O[t] = __builtin_amdgcn_mfma_f32_16x16x32_bf16(af0.s8, vf, O[t], 0, 0, 0);
            }
#pragma unroll
            for (int t = 0; t < 4; t++) {
                short8 vf = *(const short8*)(vl + 2048 + (t << 9));
                O[t] = __builtin_amdgcn_mfma_f32_16x16x32_bf16(af1.s8, vf, O[t], 0, 0, 0);
            }
        }
        __syncthreads();                 // all reads done before next scale stages

        // denominator: lane-local partial over 16 k's; reduce across quads
        lsum += __shfl_xor(lsum, 16, 64);
        lsum += __shfl_xor(lsum, 32, 64);
        // redistribute l[q] to O's row layout (q = quad*4+r) and accumulate
        float wsc = wagg[s];
#pragma unroll
        for (int r = 0; r < 4; r++) {
            int sl = (lane & 48) | (((lane >> 4) << 2) + r);
            float lr = __shfl(lsum, sl, 64);
            float linv = wsc / lr;
#pragma unroll
            for (int t = 0; t < 4; t++) fin[t][r] += O[t][r] * linv;
        }
    }
#pragma unroll
    for (int r = 0; r < 4; r++) {
        size_t rbase = ((size_t)(qrow0 + (quad << 2) + r) << 10) + (h << 6) + lq;
#pragma unroll
        for (int t = 0; t < 4; t++)
            attb[rbase + (t << 4)] = f2bf(fin[t][r]);
    }
}

// ---------------------------------------------------------------- add-N + LN
// out = LN(a + sum_j pb[j*pstride + .]); OBF: also write bf16 copy.
// Partial-slab reads are nontemporal (read-once streams).
template <int NP, int OBF>
__global__ __launch_bounds__(256) void addlnN_kernel(
    const float* __restrict__ a, const float* __restrict__ pb, size_t pstride,
    const float* __restrict__ gam, const float* __restrict__ bet,
    float* __restrict__ out, short* __restrict__ outb) {
    __shared__ float redA[4], redB[4];
    int row = blockIdx.x, tid = threadIdx.x;
    size_t base = (size_t)row * DD + (tid << 2);
    float4v av = *(const float4v*)&a[base];
    float s0 = av[0], s1 = av[1], s2 = av[2], s3 = av[3];
#pragma unroll
    for (int j = 0; j < NP; j++) {
        float4v pv = __builtin_nontemporal_load(
            (const float4v*)&pb[(size_t)j * pstride + base]);
        s0 += pv[0]; s1 += pv[1]; s2 += pv[2]; s3 += pv[3];
    }
    float lsum = s0 + s1 + s2 + s3;
    float lsq = s0 * s0 + s1 * s1 + s2 * s2 + s3 * s3;
#pragma unroll
    for (int o = 32; o > 0; o >>= 1) {
        lsum += __shfl_down(lsum, o, 64);
        lsq += __shfl_down(lsq, o, 64);
    }
    int lane = tid & 63, wid = tid >> 6;
    if (lane == 0) { redA[wid] = lsum; redB[wid] = lsq; }
    __syncthreads();
    float tsum = redA[0] + redA[1] + redA[2] + redA[3];
    float tsq = redB[0] + redB[1] + redB[2] + redB[3];
    float mean = tsum * (1.0f / DD);
    float var = tsq * (1.0f / DD) - mean * mean;
    float rstd = rsqrtf(var + 1e-5f);
    float4v gv = *(const float4v*)&gam[tid << 2];
    float4v bev = *(const float4v*)&bet[tid << 2];
    float4v o;
    o[0] = (s0 - mean) * rstd * gv[0] + bev[0];
    o[1] = (s1 - mean) * rstd * gv[1] + bev[1];
    o[2] = (s2 - mean) * rstd * gv[2] + bev[2];
    o[3] = (s3 - mean) * rstd * gv[3] + bev[3];
    *(float4v*)&out[base] = o;
    if (OBF) {
        ushort4 u;
        u.x = (unsigned short)f2bf(o[0]);
        u.y = (unsigned short)f2bf(o[1]);
        u.z = (unsigned short)f2bf(o[2]);
        u.w = (unsigned short)f2bf(o[3]);
        *(ushort4*)&outb[base] = u;
    }
}

// ---------------------------------------------------------------- launcher
extern "C" void kernel_launch(void* const* d_in, const int* in_sizes, int n_in,
                              void* d_out, int out_size, void* d_ws, size_t ws_size,
                              hipStream_t stream) {
    (void)in_sizes; (void)n_in; (void)out_size; (void)ws_size;
    const float* x   = (const float*)d_in[0];
    const float* Wdc = (const float*)d_in[1];
    const float* bdc = (const float*)d_in[2];
    const float* Wdec= (const float*)d_in[3];
    const float* Wq  = (const float*)d_in[4];
    const float* Wk  = (const float*)d_in[5];
    const float* Wv  = (const float*)d_in[6];
    const float* Wo  = (const float*)d_in[7];
    const float* agg = (const float*)d_in[8];
    const float* g1  = (const float*)d_in[9];
    const float* be1 = (const float*)d_in[10];
    const float* g2  = (const float*)d_in[11];
    const float* be2 = (const float*)d_in[12];
    const float* W1  = (const float*)d_in[13];
    const float* b1  = (const float*)d_in[14];
    const float* W2  = (const float*)d_in[15];
    const float* b2  = (const float*)d_in[16];
    float* out = (float*)d_out;

    float* ws = (float*)d_ws;
    size_t off = 0;
    auto alloc = [&](size_t nfloats) { float* p = ws + off; off += nfloats; return p; };
    const size_t M1 = 1024 * 1024;
    short* wdc_bt  = (short*)alloc(3 * M1 / 2);
    short* wdec_bt = (short*)alloc(3 * M1);
    short* wq4t    = (short*)alloc(2 * M1);
    short* wkvt    = (short*)alloc(4 * M1);
    short* wot     = (short*)alloc(M1 / 2);
    short* w1t     = (short*)alloc(2 * M1);
    short* w2t     = (short*)alloc(2 * M1);
    float* wagg    = alloc(64);
    short* xpad    = (short*)alloc(2105344);
    // activation buffers: contiguous rows 0..7679 for grouped KV GEMM
    short* xcb     = (short*)alloc(2 * M1);         // rows [0,4096)
    short* s1b     = (short*)alloc(M1);             // rows [4096,6144)
    short* s2b     = (short*)alloc(M1 / 2);         // rows [6144,7168)
    short* s3b     = (short*)alloc(M1 / 4);         // rows [7168,7680)
    short* qb4     = (short*)alloc(8 * M1);         // later FFN hidden; conv partials first
    short* kvall   = (short*)alloc(7 * M1 + M1 / 2);// V-half rows; FFN2 partials later
    short* kfrall  = (short*)alloc(3 * M1 + 3 * M1 / 4);
    short* vfrall  = (short*)alloc(3 * M1 + 3 * M1 / 4);
    short* attb    = (short*)alloc(2 * M1);
    float* x1      = alloc(4 * M1);
    short* x1b     = (short*)alloc(2 * M1);
    float* pkbuf   = alloc(8 * M1);                 // Wo/dec split-K partials
    short* hb      = qb4;                           // FFN hidden [4096][4096] bf16
    float* convp   = (float*)qb4;                   // conv tap partials (12M fp32:
                                                    //  qb4 8M + kvall first 4M, contiguous)
    float* pk4     = (float*)kvall;                 // FFN2 4x4M fp32 partials
                                                    //  (kvall+kfrall+vfrall+1M of attb; all
                                                    //  dead after attention / Wo)

    dim3 blk(256);
    // ---- fused prep
    prep_all_kernel<<<dim3(74817), blk, 0, stream>>>(
        Wdc, Wdec, Wq, Wk, Wv, Wo, W1, W2, x, agg,
        wdc_bt, wdec_bt, wq4t, wkvt, wot, w1t, w2t, xpad, wagg,
        out + (size_t)DB * DL * DD);

    // 1. dilated conv: tap-split x3 + relu/bias combine
    convdil_pk_kernel<<<dim3(DD / 128, DB * DL / 128, 3), blk, 0, stream>>>(
        xpad, wdc_bt, convp);
    convcomb_kernel<<<dim3(4 * M1 / (256 * 4)), blk, 0, stream>>>(convp, bdc, xcb);

    // 2. decomposition convs: split-K x4 each (512/256/128 blocks) + sum-cast
    mgemm_pk_kernel<<<dim3(8, 16, 4), blk, 0, stream>>>(
        xcb, wdec_bt, nullptr, pkbuf, 2048, DD, 2 * DD, 512);
    sumcast4_kernel<<<dim3(2 * M1 / 1024), blk, 0, stream>>>(pkbuf, 2 * M1, s1b);
    mgemm_pk_kernel<<<dim3(8, 8, 4), blk, 0, stream>>>(
        s1b, wdec_bt + 2 * M1, nullptr, pkbuf, 1024, DD, 2 * DD, 512);
    sumcast4_kernel<<<dim3(M1 / 1024), blk, 0, stream>>>(pkbuf, M1, s2b);
    mgemm_pk_kernel<<<dim3(8, 4, 4), blk, 0, stream>>>(
        s2b, wdec_bt + 4 * M1, nullptr, pkbuf, 512, DD, 2 * DD, 512);
    sumcast4_kernel<<<dim3(M1 / 2048), blk, 0, stream>>>(pkbuf, M1 / 2, s3b);

    // 3a. batched Q projection (all 4 scales, N=4096)
    mgemm_kernel<0, 1><<<dim3(32, 32), blk, 0, stream>>>(
        xcb, wq4t, nullptr, qb4, DB * DL, 4 * DD, DD);

    // 3b. grouped K|V projection (K-half straight to fragment layout)
    kvgemm_kernel<<<dim3(16, 60), blk, 0, stream>>>(xcb, wkvt, kvall, kfrall);

    // 3c. V fragment prep (k-permuted, slot-group-major for LDS staging)
    vfrag_all_kernel<<<dim3(7680), blk, 0, stream>>>(kvall, vfrall);

    // 3d. fused attention, block-shared K/V via LDS double-buffer,
    //     in-register P, XCD-locality swizzled
    attn_fused9_kernel<<<dim3(DB * DH, DL / 64), blk, 0, stream>>>(
        qb4, kfrall, vfrall, wagg, attb);

    // 4. shared output projection (split-K x2)
    mgemm_pk_kernel<<<dim3(8, 32, 2), blk, 0, stream>>>(
        attb, wot, nullptr, pkbuf, DB * DL, DD, DD, DD / 2);

    // 5. residual + LN1 (2 partials)
    addlnN_kernel<2, 1><<<dim3(DB * DL), blk, 0, stream>>>(
        x, pkbuf, 4 * M1, g1, be1, x1, x1b);

    // 6. FFN: GELU GEMM then split-K x4 down-projection (1024 blocks)
    mgemm_kernel<1, 1><<<dim3(DF / 128, (DB * DL) / 128), blk, 0, stream>>>(
        x1b, w1t, b1, hb, DB * DL, DF, DD);
    mgemm_pk_kernel<<<dim3(8, 32, 4), blk, 0, stream>>>(
        hb, w2t, b2, pk4, DB * DL, DD, DF, DF / 4);

    // 7. residual + LN2 -> out (4 partials)
    addlnN_kernel<4, 0><<<dim3(DB * DL), blk, 0, stream>>>(
        x1, pk4, 4 * M1, g2, be2, out, nullptr);
}